// Round 2
// baseline (702.144 us; speedup 1.0000x reference)
//
#include <hip/hip_runtime.h>

typedef __bf16 bf16x8 __attribute__((ext_vector_type(8)));
typedef float f32x4 __attribute__((ext_vector_type(4)));
typedef float f32x16 __attribute__((ext_vector_type(16)));

#define BATCH 4
#define SEQ   2048
#define DIM   1024
#define NH    16
#define HD    64
#define ECF   0.18033688f   // log2(e)/8 : folds 1/sqrt(64) into exp2

__device__ __forceinline__ unsigned short f2bf(float f) {
  union { float f; unsigned u; } v; v.f = f;
  unsigned u = v.u;
  u += 0x7FFF + ((u >> 16) & 1);   // round-to-nearest-even
  return (unsigned short)(u >> 16);
}

__device__ __forceinline__ void g2lds16(const unsigned short* g, unsigned short* l) {
  __builtin_amdgcn_global_load_lds(
      (const __attribute__((address_space(1))) unsigned int*)g,
      (__attribute__((address_space(3))) unsigned int*)l, 16, 0, 0);
}

// scalar-cast pack (compiler emits v_cvt_pk_bf16_f32; m240: faster than hand asm)
__device__ __forceinline__ unsigned packbf(float a, float b) {
  __bf16 lo = (__bf16)a, hi = (__bf16)b;
  unsigned short ul = __builtin_bit_cast(unsigned short, lo);
  unsigned short uh = __builtin_bit_cast(unsigned short, hi);
  return (unsigned)ul | ((unsigned)uh << 16);
}

// ------------- fused cast fp32 -> bf16 (x, Wq*EC, Wk, Wv) -------------
__global__ __launch_bounds__(256) void cast_all_kernel(
    const float* __restrict__ x,  const float* __restrict__ Wq,
    const float* __restrict__ Wk, const float* __restrict__ Wv,
    unsigned short* __restrict__ xb,  unsigned short* __restrict__ wqb,
    unsigned short* __restrict__ wkb, unsigned short* __restrict__ wvb) {
  const int XG = (BATCH * SEQ * DIM) / 8;   // 1048576
  const int WG = (DIM * DIM) / 8;           // 131072
  int i = blockIdx.x * 256 + threadIdx.x;
  const float* in; unsigned short* out; float sc = 1.0f; int off;
  if (i < XG)               { in = x;  out = xb;  off = i; }
  else if (i < XG + WG)     { in = Wq; out = wqb; off = i - XG; sc = ECF; }
  else if (i < XG + 2 * WG) { in = Wk; out = wkb; off = i - XG - WG; }
  else                      { in = Wv; out = wvb; off = i - XG - 2 * WG; }
  const float4* p = (const float4*)in + (size_t)off * 2;
  float4 a = p[0], b = p[1];
  unsigned short r[8];
  r[0] = f2bf(a.x * sc); r[1] = f2bf(a.y * sc); r[2] = f2bf(a.z * sc); r[3] = f2bf(a.w * sc);
  r[4] = f2bf(b.x * sc); r[5] = f2bf(b.y * sc); r[6] = f2bf(b.z * sc); r[7] = f2bf(b.w * sc);
  *(uint4*)&out[(size_t)off * 8] = *(uint4*)r;
}

// ---------------- fused QKV projection GEMM (unchanged) ---------------
__global__ __launch_bounds__(256) void gemm_qkv(
    const unsigned short* __restrict__ A,
    const unsigned short* __restrict__ Wqp, const unsigned short* __restrict__ Wkp,
    const unsigned short* __restrict__ Wvp,
    const float* __restrict__ bqp, const float* __restrict__ bkp,
    const float* __restrict__ bvp,
    unsigned short* __restrict__ oq, unsigned short* __restrict__ ok,
    unsigned short* __restrict__ ov) {
  __shared__ unsigned short As[128 * 32];
  __shared__ unsigned short Bs[128 * 32];
  const int z = blockIdx.z;
  const unsigned short* W = (z == 0) ? Wqp : (z == 1) ? Wkp : Wvp;
  const float* bias        = (z == 0) ? bqp : (z == 1) ? bkp : bvp;
  unsigned short* outp     = (z == 0) ? oq  : (z == 1) ? ok  : ov;
  const float bsc          = (z == 0) ? ECF : 1.0f;   // bq scaled like Wq
  const int mode = (z == 2) ? 1 : 0;

  const int tid  = threadIdx.x;
  const int wave = tid >> 6;
  const int lane = tid & 63;
  const int lm   = lane & 15;
  const int qd   = lane >> 4;
  const int m0 = blockIdx.x * 128;
  const int n0 = blockIdx.y * 128;
  const int wm = (wave >> 1) * 64;
  const int wn = (wave & 1) * 64;

  const f32x4 zero = {0.f, 0.f, 0.f, 0.f};
  f32x4 acc[4][4];
#pragma unroll
  for (int i = 0; i < 4; ++i)
#pragma unroll
    for (int j = 0; j < 4; ++j) acc[i][j] = zero;

  const int srow = tid >> 2;                               // 0..63
  const int scol = (((tid & 3) ^ ((tid >> 3) & 3))) * 8;   // swizzled source chunk
  const int cs   = (qd ^ ((lm >> 1) & 3)) * 8;             // swizzled read chunk

  for (int kt = 0; kt < DIM; kt += 32) {
    __syncthreads();
    g2lds16(&A[(size_t)(m0 + srow) * DIM + kt + scol],       &As[(size_t)tid * 8]);
    g2lds16(&A[(size_t)(m0 + 64 + srow) * DIM + kt + scol],  &As[2048 + (size_t)tid * 8]);
    g2lds16(&W[(size_t)(n0 + srow) * DIM + kt + scol],       &Bs[(size_t)tid * 8]);
    g2lds16(&W[(size_t)(n0 + 64 + srow) * DIM + kt + scol],  &Bs[2048 + (size_t)tid * 8]);
    __syncthreads();

    bf16x8 af[4], bfr[4];
#pragma unroll
    for (int i = 0; i < 4; ++i) af[i]  = *(const bf16x8*)&As[(wm + i * 16 + lm) * 32 + cs];
#pragma unroll
    for (int j = 0; j < 4; ++j) bfr[j] = *(const bf16x8*)&Bs[(wn + j * 16 + lm) * 32 + cs];
#pragma unroll
    for (int i = 0; i < 4; ++i)
#pragma unroll
      for (int j = 0; j < 4; ++j)
        acc[i][j] = __builtin_amdgcn_mfma_f32_16x16x32_bf16(af[i], bfr[j], acc[i][j], 0, 0, 0);
  }

#pragma unroll
  for (int j = 0; j < 4; ++j) {
    int col = n0 + wn + j * 16 + lm;       // n index
    float bb = bias[col] * bsc;
    int h = col >> 6, hd = col & 63;
#pragma unroll
    for (int i = 0; i < 4; ++i) {
      int rowb = m0 + wm + i * 16 + qd * 4;   // base m index (r=0)
      int b = rowb >> 11, s = rowb & 2047;
      if (mode == 0) {
#pragma unroll
        for (int r = 0; r < 4; ++r) {
          float v = acc[i][j][r] + bb;
          outp[((size_t)(b * NH + h) * SEQ + (s + r)) * HD + hd] = f2bf(v);
        }
      } else {
        unsigned short pk[4];
#pragma unroll
        for (int r = 0; r < 4; ++r) pk[r] = f2bf(acc[i][j][r] + bb);
        size_t idx = ((size_t)(b * NH + h) * HD + hd) * SEQ + s;
        *(uint2*)&outp[idx] = *(uint2*)pk;
      }
    }
  }
}

// -------- flash attention: 8 waves, in-block split-K, 32x32 MFMA ------
// R7: occupancy was the limiter (2 waves/SIMD; VALU 48% + MFMA 30% serialize
// within a wave). In-block split-K: waves 0-3 = q-chunks x keys [0,1024),
// waves 4-7 = same q-chunks x keys [1024,2048). 4096 waves total ->
// 4 waves/SIMD, while q-rows/wave stays 64 so DS reads/wave-tile unchanged.
// No running max is used (un-maxed softmax, bounded scores), so split-K
// partials are purely additive: O = O_A + O_B, l = l_A + l_B.
// Partials combine via a 64KB LDS overlay on the K/V buffers; each wave
// combines one 32-row half (balanced epilogue). T5 setprio around MFMA.
__global__ __launch_bounds__(512, 4) void flash_kernel(
    const unsigned short* __restrict__ Qp, const unsigned short* __restrict__ Kp,
    const unsigned short* __restrict__ Vp, float* __restrict__ out) {
  // [0..16383]  : K tiles  [buf][stream][64key][64d] swizzled (32KB)
  // [16384..]   : V tiles  [buf][stream][64hd][64key] swizzled (32KB)
  // epilogue overlay: 16384 floats = partial O [qbhalf][qc][32row][64hd]
  __shared__ __align__(16) unsigned short smem[32768];
  __shared__ float Lpart[2][4][32];
  __shared__ float Ls[4][2][32];

  const int tid  = threadIdx.x;   // 0..511
  const int w    = tid >> 6;      // wave 0..7
  const int sgrp = w >> 2;        // key-half group: 0 -> [0,1024), 1 -> [1024,2048)
  const int qc   = w & 3;         // q-chunk within block
  const int lane = tid & 63;
  const int l31  = lane & 31;
  const int hi   = lane >> 5;
  const int bh   = blockIdx.y;
  const int q0blk = blockIdx.x * 256;
  const int wq0  = q0blk + qc * 64;

  const unsigned short* Qb = Qp + (size_t)bh * (SEQ * HD);
  const unsigned short* Kb = Kp + (size_t)bh * (SEQ * HD);
  const unsigned short* Vb = Vp + (size_t)bh * (HD * SEQ);

  unsigned short* Ksm = smem;
  unsigned short* Vsm = smem + 16384;

  // Q in registers: 64 rows/wave = 2 row-blocks x 4 d-blocks
  bf16x8 qf[2][4];
#pragma unroll
  for (int qb = 0; qb < 2; ++qb)
#pragma unroll
    for (int db = 0; db < 4; ++db)
      qf[qb][db] = *(const bf16x8*)&Qb[(size_t)(wq0 + qb * 32 + l31) * HD + db * 16 + hi * 8];

  f32x16 o[2][2];
#pragma unroll
  for (int qb = 0; qb < 2; ++qb)
#pragma unroll
    for (int jn = 0; jn < 2; ++jn)
#pragma unroll
      for (int r = 0; r < 16; ++r) o[qb][jn][r] = 0.f;
  float psum[2] = {0.f, 0.f};

  // staging: 512 threads, each stages one 16B chunk per {K,V} x {stream A,B}
  const int sr = tid >> 3;                    // staging row 0..63
  const int sp = ((tid & 7) ^ (sr & 7)) * 8;  // pre-swizzled col chunk (rule 21)

  auto STAGE = [&](int buf, int ktile) {
    const int kA = ktile * 64;
    g2lds16(&Kb[(size_t)(kA + sr) * HD + sp],          &Ksm[buf * 8192 + tid * 8]);
    g2lds16(&Kb[(size_t)(1024 + kA + sr) * HD + sp],   &Ksm[buf * 8192 + 4096 + tid * 8]);
    g2lds16(&Vb[(size_t)sr * SEQ + kA + sp],           &Vsm[buf * 8192 + tid * 8]);
    g2lds16(&Vb[(size_t)sr * SEQ + 1024 + kA + sp],    &Vsm[buf * 8192 + 4096 + tid * 8]);
  };

  const int r7 = l31 & 7;   // read-side swizzle key

  auto COMPUTE = [&](int buf) {
    const unsigned short* Kc = &Ksm[buf * 8192 + sgrp * 4096];
    const unsigned short* Vc = &Vsm[buf * 8192 + sgrp * 4096];
    bf16x8 pa[2][4];   // PV A-fragments [qb][ks]
#pragma unroll
    for (int kb = 0; kb < 2; ++kb) {
      f32x16 s0 = {0,0,0,0,0,0,0,0,0,0,0,0,0,0,0,0};
      f32x16 s1 = {0,0,0,0,0,0,0,0,0,0,0,0,0,0,0,0};
      __builtin_amdgcn_s_setprio(1);
#pragma unroll
      for (int db = 0; db < 4; ++db) {
        int ch = (db * 2 + hi) ^ r7;
        bf16x8 kf = *(const bf16x8*)&Kc[((kb * 32 + l31) * 8 + ch) * 8];
        s0 = __builtin_amdgcn_mfma_f32_32x32x16_bf16(kf, qf[0][db], s0, 0, 0, 0);
        s1 = __builtin_amdgcn_mfma_f32_32x32x16_bf16(kf, qf[1][db], s1, 0, 0, 0);
      }
      __builtin_amdgcn_s_setprio(0);
      // in-register softmax-numerator + fragment rebuild (T12)
#pragma unroll
      for (int qb = 0; qb < 2; ++qb) {
        const f32x16 s = qb ? s1 : s0;
        float p[16];
#pragma unroll
        for (int r = 0; r < 16; ++r) p[r] = __builtin_amdgcn_exp2f(s[r]);
        psum[qb] += ((p[0] + p[1]) + (p[2] + p[3])) + ((p[4] + p[5]) + (p[6] + p[7]))
                  + ((p[8] + p[9]) + (p[10] + p[11])) + ((p[12] + p[13]) + (p[14] + p[15]));
        unsigned w01 = packbf(p[0],  p[1]),  w23 = packbf(p[2],  p[3]);
        unsigned w45 = packbf(p[4],  p[5]),  w67 = packbf(p[6],  p[7]);
        unsigned w89 = packbf(p[8],  p[9]),  wab = packbf(p[10], p[11]);
        unsigned wcd = packbf(p[12], p[13]), wef = packbf(p[14], p[15]);
        asm volatile("v_permlane32_swap_b32 %0, %1" : "+v"(w01), "+v"(w45));
        asm volatile("v_permlane32_swap_b32 %0, %1" : "+v"(w23), "+v"(w67));
        asm volatile("v_permlane32_swap_b32 %0, %1" : "+v"(w89), "+v"(wcd));
        asm volatile("v_permlane32_swap_b32 %0, %1" : "+v"(wab), "+v"(wef));
        union { unsigned u[4]; bf16x8 v; } flo, fhi;
        flo.u[0] = w01; flo.u[1] = w23; flo.u[2] = w45; flo.u[3] = w67;
        fhi.u[0] = w89; fhi.u[1] = wab; fhi.u[2] = wcd; fhi.u[3] = wef;
        pa[qb][kb * 2]     = flo.v;
        pa[qb][kb * 2 + 1] = fhi.v;
      }
    }
    // O += P V
    __builtin_amdgcn_s_setprio(1);
#pragma unroll
    for (int ks = 0; ks < 4; ++ks) {
#pragma unroll
      for (int jn = 0; jn < 2; ++jn) {
        int ch = (ks * 2 + hi) ^ r7;
        bf16x8 vf = *(const bf16x8*)&Vc[((jn * 32 + l31) * 8 + ch) * 8];
        o[0][jn] = __builtin_amdgcn_mfma_f32_32x32x16_bf16(pa[0][ks], vf, o[0][jn], 0, 0, 0);
        o[1][jn] = __builtin_amdgcn_mfma_f32_32x32x16_bf16(pa[1][ks], vf, o[1][jn], 0, 0, 0);
      }
    }
    __builtin_amdgcn_s_setprio(0);
  };

  STAGE(0, 0);
  for (int kt = 0; kt < 16; kt += 2) {
    __syncthreads();            // buf0 staged; prior reads of buf1 done
    STAGE(1, kt + 1);
    COMPUTE(0);
    __syncthreads();            // buf1 staged; reads of buf0 done
    if (kt + 2 < 16) STAGE(0, kt + 2);
    COMPUTE(1);
  }

  // ---- split-K combine via LDS overlay (each wave combines one 32-row half)
  __syncthreads();              // all K/V tile reads done -> overlay safe
  float* Op = (float*)smem;     // [qbhalf][qc][32 rows][64 hd]
  const int b = bh >> 4, hh = bh & 15;

#define EPI_WRITE(QB) do {                                                   \
    _Pragma("unroll")                                                        \
    for (int r = 0; r < 16; ++r) {                                           \
      int crow = (r & 3) + 8 * (r >> 2) + 4 * hi;                            \
      float* dst = &Op[(((QB) * 4 + qc) * 32 + crow) * 64 + l31];            \
      dst[0]  = o[QB][0][r];                                                 \
      dst[32] = o[QB][1][r];                                                 \
    }                                                                        \
    float lW = psum[QB] + __shfl_xor(psum[QB], 32);                          \
    if (hi == 0) Lpart[QB][qc][l31] = lW;                                    \
  } while (0)

#define EPI_COMBINE(QB) do {                                                 \
    float lC = psum[QB] + __shfl_xor(psum[QB], 32);                          \
    if (hi == 0) Ls[qc][QB][l31] = 1.0f / (lC + Lpart[QB][qc][l31]);         \
    asm volatile("s_waitcnt lgkmcnt(0)" ::: "memory");                       \
    _Pragma("unroll")                                                        \
    for (int r = 0; r < 16; ++r) {                                           \
      int crow = (r & 3) + 8 * (r >> 2) + 4 * hi;                            \
      float inv = Ls[qc][QB][crow];                                          \
      const float* src = &Op[(((QB) * 4 + qc) * 32 + crow) * 64 + l31];      \
      int qrow = q0blk + qc * 64 + (QB) * 32 + crow;                         \
      float* po = &out[(size_t)(b * SEQ + qrow) * DIM + hh * HD + l31];      \
      po[0]  = (o[QB][0][r] + src[0])  * inv;                                \
      po[32] = (o[QB][1][r] + src[32]) * inv;                                \
    }                                                                        \
  } while (0)

  // group 0 combines rows [0,32) (writes its [32,64) partial), group 1 mirrors
  if (sgrp == 0) EPI_WRITE(1); else EPI_WRITE(0);
  __syncthreads();
  if (sgrp == 0) EPI_COMBINE(0); else EPI_COMBINE(1);

#undef EPI_WRITE
#undef EPI_COMBINE
}

extern "C" void kernel_launch(void* const* d_in, const int* in_sizes, int n_in,
                              void* d_out, int out_size, void* d_ws, size_t ws_size,
                              hipStream_t stream) {
  const float* x  = (const float*)d_in[0];
  const float* Wq = (const float*)d_in[1];
  const float* bq = (const float*)d_in[2];
  const float* Wk = (const float*)d_in[3];
  const float* bk = (const float*)d_in[4];
  const float* Wv = (const float*)d_in[5];
  const float* bv = (const float*)d_in[6];
  float* out = (float*)d_out;

  unsigned short* ws = (unsigned short*)d_ws;
  const size_t XE = (size_t)BATCH * SEQ * DIM;   // 8388608
  const size_t WE = (size_t)DIM * DIM;           // 1048576
  unsigned short* xb  = ws;
  unsigned short* wqb = xb + XE;
  unsigned short* wkb = wqb + WE;
  unsigned short* wvb = wkb + WE;
  unsigned short* qb  = wvb + WE;
  unsigned short* kb  = qb + XE;
  unsigned short* vb  = kb + XE;

  const int total_groups = (int)(XE / 8 + 3 * (WE / 8));   // 1441792
  cast_all_kernel<<<total_groups / 256, 256, 0, stream>>>(
      x, Wq, Wk, Wv, xb, wqb, wkb, wvb);

  dim3 gg(64, 8, 3);
  gemm_qkv<<<gg, 256, 0, stream>>>(xb, wqb, wkb, wvb, bq, bk, bv, qb, kb, vb);

  dim3 fg(SEQ / 256, BATCH * NH);
  flash_kernel<<<fg, 512, 0, stream>>>(qb, kb, vb, out);
}

// Round 3
// 256.317 us; speedup vs baseline: 2.7394x; 2.7394x over previous
//
#include <hip/hip_runtime.h>

typedef __bf16 bf16x8 __attribute__((ext_vector_type(8)));
typedef float f32x4 __attribute__((ext_vector_type(4)));
typedef float f32x16 __attribute__((ext_vector_type(16)));

#define BATCH 4
#define SEQ   2048
#define DIM   1024
#define NH    16
#define HD    64
#define ECF   0.18033688f   // log2(e)/8 : folds 1/sqrt(64) into exp2

__device__ __forceinline__ unsigned short f2bf(float f) {
  union { float f; unsigned u; } v; v.f = f;
  unsigned u = v.u;
  u += 0x7FFF + ((u >> 16) & 1);   // round-to-nearest-even
  return (unsigned short)(u >> 16);
}

__device__ __forceinline__ void g2lds16(const unsigned short* g, unsigned short* l) {
  __builtin_amdgcn_global_load_lds(
      (const __attribute__((address_space(1))) unsigned int*)g,
      (__attribute__((address_space(3))) unsigned int*)l, 16, 0, 0);
}

// scalar-cast pack (compiler emits v_cvt_pk_bf16_f32; m240: faster than hand asm)
__device__ __forceinline__ unsigned packbf(float a, float b) {
  __bf16 lo = (__bf16)a, hi = (__bf16)b;
  unsigned short ul = __builtin_bit_cast(unsigned short, lo);
  unsigned short uh = __builtin_bit_cast(unsigned short, hi);
  return (unsigned)ul | ((unsigned)uh << 16);
}

// ------------- fused cast fp32 -> bf16 (x, Wq*EC, Wk, Wv) -------------
__global__ __launch_bounds__(256) void cast_all_kernel(
    const float* __restrict__ x,  const float* __restrict__ Wq,
    const float* __restrict__ Wk, const float* __restrict__ Wv,
    unsigned short* __restrict__ xb,  unsigned short* __restrict__ wqb,
    unsigned short* __restrict__ wkb, unsigned short* __restrict__ wvb) {
  const int XG = (BATCH * SEQ * DIM) / 8;   // 1048576
  const int WG = (DIM * DIM) / 8;           // 131072
  int i = blockIdx.x * 256 + threadIdx.x;
  const float* in; unsigned short* out; float sc = 1.0f; int off;
  if (i < XG)               { in = x;  out = xb;  off = i; }
  else if (i < XG + WG)     { in = Wq; out = wqb; off = i - XG; sc = ECF; }
  else if (i < XG + 2 * WG) { in = Wk; out = wkb; off = i - XG - WG; }
  else                      { in = Wv; out = wvb; off = i - XG - 2 * WG; }
  const float4* p = (const float4*)in + (size_t)off * 2;
  float4 a = p[0], b = p[1];
  unsigned short r[8];
  r[0] = f2bf(a.x * sc); r[1] = f2bf(a.y * sc); r[2] = f2bf(a.z * sc); r[3] = f2bf(a.w * sc);
  r[4] = f2bf(b.x * sc); r[5] = f2bf(b.y * sc); r[6] = f2bf(b.z * sc); r[7] = f2bf(b.w * sc);
  *(uint4*)&out[(size_t)off * 8] = *(uint4*)r;
}

// ---------------- fused QKV projection GEMM (unchanged) ---------------
__global__ __launch_bounds__(256) void gemm_qkv(
    const unsigned short* __restrict__ A,
    const unsigned short* __restrict__ Wqp, const unsigned short* __restrict__ Wkp,
    const unsigned short* __restrict__ Wvp,
    const float* __restrict__ bqp, const float* __restrict__ bkp,
    const float* __restrict__ bvp,
    unsigned short* __restrict__ oq, unsigned short* __restrict__ ok,
    unsigned short* __restrict__ ov) {
  __shared__ unsigned short As[128 * 32];
  __shared__ unsigned short Bs[128 * 32];
  const int z = blockIdx.z;
  const unsigned short* W = (z == 0) ? Wqp : (z == 1) ? Wkp : Wvp;
  const float* bias        = (z == 0) ? bqp : (z == 1) ? bkp : bvp;
  unsigned short* outp     = (z == 0) ? oq  : (z == 1) ? ok  : ov;
  const float bsc          = (z == 0) ? ECF : 1.0f;   // bq scaled like Wq
  const int mode = (z == 2) ? 1 : 0;

  const int tid  = threadIdx.x;
  const int wave = tid >> 6;
  const int lane = tid & 63;
  const int lm   = lane & 15;
  const int qd   = lane >> 4;
  const int m0 = blockIdx.x * 128;
  const int n0 = blockIdx.y * 128;
  const int wm = (wave >> 1) * 64;
  const int wn = (wave & 1) * 64;

  const f32x4 zero = {0.f, 0.f, 0.f, 0.f};
  f32x4 acc[4][4];
#pragma unroll
  for (int i = 0; i < 4; ++i)
#pragma unroll
    for (int j = 0; j < 4; ++j) acc[i][j] = zero;

  const int srow = tid >> 2;                               // 0..63
  const int scol = (((tid & 3) ^ ((tid >> 3) & 3))) * 8;   // swizzled source chunk
  const int cs   = (qd ^ ((lm >> 1) & 3)) * 8;             // swizzled read chunk

  for (int kt = 0; kt < DIM; kt += 32) {
    __syncthreads();
    g2lds16(&A[(size_t)(m0 + srow) * DIM + kt + scol],       &As[(size_t)tid * 8]);
    g2lds16(&A[(size_t)(m0 + 64 + srow) * DIM + kt + scol],  &As[2048 + (size_t)tid * 8]);
    g2lds16(&W[(size_t)(n0 + srow) * DIM + kt + scol],       &Bs[(size_t)tid * 8]);
    g2lds16(&W[(size_t)(n0 + 64 + srow) * DIM + kt + scol],  &Bs[2048 + (size_t)tid * 8]);
    __syncthreads();

    bf16x8 af[4], bfr[4];
#pragma unroll
    for (int i = 0; i < 4; ++i) af[i]  = *(const bf16x8*)&As[(wm + i * 16 + lm) * 32 + cs];
#pragma unroll
    for (int j = 0; j < 4; ++j) bfr[j] = *(const bf16x8*)&Bs[(wn + j * 16 + lm) * 32 + cs];
#pragma unroll
    for (int i = 0; i < 4; ++i)
#pragma unroll
      for (int j = 0; j < 4; ++j)
        acc[i][j] = __builtin_amdgcn_mfma_f32_16x16x32_bf16(af[i], bfr[j], acc[i][j], 0, 0, 0);
  }

#pragma unroll
  for (int j = 0; j < 4; ++j) {
    int col = n0 + wn + j * 16 + lm;       // n index
    float bb = bias[col] * bsc;
    int h = col >> 6, hd = col & 63;
#pragma unroll
    for (int i = 0; i < 4; ++i) {
      int rowb = m0 + wm + i * 16 + qd * 4;   // base m index (r=0)
      int b = rowb >> 11, s = rowb & 2047;
      if (mode == 0) {
#pragma unroll
        for (int r = 0; r < 4; ++r) {
          float v = acc[i][j][r] + bb;
          outp[((size_t)(b * NH + h) * SEQ + (s + r)) * HD + hd] = f2bf(v);
        }
      } else {
        unsigned short pk[4];
#pragma unroll
        for (int r = 0; r < 4; ++r) pk[r] = f2bf(acc[i][j][r] + bb);
        size_t idx = ((size_t)(b * NH + h) * HD + hd) * SEQ + s;
        *(uint2*)&outp[idx] = *(uint2*)pk;
      }
    }
  }
}

// -------- flash attention: 4 waves (2 qc x 2 split-K), 32x32 MFMA -----
// R8: R7's split-K idea with the VGPR disaster fixed. Wave needs ~150 VGPR
// (o=64, qf=32, s=32 irreducible at 64 q-rows/wave) -> 3 waves/SIMD max.
// 256-thread blocks quantize occupancy in 4-wave steps: 3 blocks/CU =
// 12 waves/CU (vs R6's 8). __launch_bounds__(256,3): cap ~170, NO spill
// (R7's (512,4) was honored as 4 blocks/CU -> 64-VGPR cap -> 2.2GB scratch).
// Block = 128 q-rows x full keys; waves: qc in {0,1} x sgrp in {0,1}
// (keys [0,1024) / [1024,2048)), 32-key steps, dbuf LDS = 32KB -> 3 blk/CU.
// Un-maxed softmax -> split-K partials additive; LDS-overlay combine.
// T1 XCD-chunked swizzle: all 16 q-blocks of one head land on one XCD.
__global__ __launch_bounds__(256, 3) void flash_kernel(
    const unsigned short* __restrict__ Qp, const unsigned short* __restrict__ Kp,
    const unsigned short* __restrict__ Vp, float* __restrict__ out) {
  // layout per buf (8192 ushorts): K0[32][64] | K1[32][64] | V[64][64 keycomb]
  // keycomb = sgrp*32 + key ; rows are 128B = 8 chunks, XOR-swizzle ^(row&7)
  __shared__ __align__(16) unsigned short smem[16384];   // 32KB (2 bufs)
  __shared__ float Lpart[2][2][32];   // [qc][qb][row]
  __shared__ float Ls[2][2][32];

  const int tid  = threadIdx.x;   // 0..255
  const int w    = tid >> 6;      // wave 0..3
  const int qc   = w & 1;
  const int sgrp = w >> 1;        // 0 -> keys [0,1024), 1 -> [1024,2048)
  const int lane = tid & 63;
  const int l31  = lane & 31;
  const int hi   = lane >> 5;

  // T1: hw dispatch id -> XCD-chunked logical id (1024 blocks, 8 XCDs)
  const int hw  = blockIdx.y * 16 + blockIdx.x;
  const int lid = (hw & 7) * 128 + (hw >> 3);
  const int bh  = lid >> 4;
  const int q0blk = (lid & 15) * 128;
  const int wq0 = q0blk + qc * 64;

  const unsigned short* Qb = Qp + (size_t)bh * (SEQ * HD);
  const unsigned short* Kb = Kp + (size_t)bh * (SEQ * HD);
  const unsigned short* Vb = Vp + (size_t)bh * (HD * SEQ);

  // Q in registers: 64 rows/wave = 2 row-blocks x 4 d-blocks
  bf16x8 qf[2][4];
#pragma unroll
  for (int qb = 0; qb < 2; ++qb)
#pragma unroll
    for (int db = 0; db < 4; ++db)
      qf[qb][db] = *(const bf16x8*)&Qb[(size_t)(wq0 + qb * 32 + l31) * HD + db * 16 + hi * 8];

  f32x16 o[2][2];
#pragma unroll
  for (int qb = 0; qb < 2; ++qb)
#pragma unroll
    for (int jn = 0; jn < 2; ++jn)
#pragma unroll
      for (int r = 0; r < 16; ++r) o[qb][jn][r] = 0.f;
  float psum[2] = {0.f, 0.f};

  // K staging: 256 chunks per sgrp-tile; thread t -> row t>>3, pos t&7
  const int sr = tid >> 3;
  const int sp = ((tid & 7) ^ (sr & 7)) * 8;   // pre-swizzled source col
  // V staging: 512 chunks (rows 0..63); chunks tid and tid+256
  const int vr0 = tid >> 3,         vs0 = (tid & 7) ^ (vr0 & 7);
  const int vr1 = (tid + 256) >> 3, vs1 = (tid & 7) ^ (vr1 & 7);

  auto STAGE = [&](int buf, int kt) {
    const int k0 = kt * 32;
    unsigned short* base = &smem[buf * 8192];
    g2lds16(&Kb[(size_t)(k0 + sr) * HD + sp],        &base[tid * 8]);
    g2lds16(&Kb[(size_t)(1024 + k0 + sr) * HD + sp], &base[2048 + tid * 8]);
    g2lds16(&Vb[(size_t)vr0 * SEQ + (vs0 >> 2) * 1024 + k0 + (vs0 & 3) * 8],
            &base[4096 + tid * 8]);
    g2lds16(&Vb[(size_t)vr1 * SEQ + (vs1 >> 2) * 1024 + k0 + (vs1 & 3) * 8],
            &base[4096 + 2048 + tid * 8]);
  };

  const int r7 = l31 & 7;   // read-side swizzle key

  auto COMPUTE = [&](int buf) {
    const unsigned short* Kc = &smem[buf * 8192 + sgrp * 2048];
    const unsigned short* Vc = &smem[buf * 8192 + 4096];
    f32x16 s0 = {0,0,0,0,0,0,0,0,0,0,0,0,0,0,0,0};
    f32x16 s1 = {0,0,0,0,0,0,0,0,0,0,0,0,0,0,0,0};
    __builtin_amdgcn_s_setprio(1);
#pragma unroll
    for (int db = 0; db < 4; ++db) {
      int ch = (db * 2 + hi) ^ r7;
      bf16x8 kf = *(const bf16x8*)&Kc[(l31 * 8 + ch) * 8];
      s0 = __builtin_amdgcn_mfma_f32_32x32x16_bf16(kf, qf[0][db], s0, 0, 0, 0);
      s1 = __builtin_amdgcn_mfma_f32_32x32x16_bf16(kf, qf[1][db], s1, 0, 0, 0);
    }
    __builtin_amdgcn_s_setprio(0);
    bf16x8 pa[2][2];   // [qb][16-key slot]
#pragma unroll
    for (int qb = 0; qb < 2; ++qb) {
      const f32x16 s = qb ? s1 : s0;
      float p[16];
#pragma unroll
      for (int r = 0; r < 16; ++r) p[r] = __builtin_amdgcn_exp2f(s[r]);
      psum[qb] += ((p[0] + p[1]) + (p[2] + p[3])) + ((p[4] + p[5]) + (p[6] + p[7]))
                + ((p[8] + p[9]) + (p[10] + p[11])) + ((p[12] + p[13]) + (p[14] + p[15]));
      unsigned w01 = packbf(p[0],  p[1]),  w23 = packbf(p[2],  p[3]);
      unsigned w45 = packbf(p[4],  p[5]),  w67 = packbf(p[6],  p[7]);
      unsigned w89 = packbf(p[8],  p[9]),  wab = packbf(p[10], p[11]);
      unsigned wcd = packbf(p[12], p[13]), wef = packbf(p[14], p[15]);
      asm volatile("v_permlane32_swap_b32 %0, %1" : "+v"(w01), "+v"(w45));
      asm volatile("v_permlane32_swap_b32 %0, %1" : "+v"(w23), "+v"(w67));
      asm volatile("v_permlane32_swap_b32 %0, %1" : "+v"(w89), "+v"(wcd));
      asm volatile("v_permlane32_swap_b32 %0, %1" : "+v"(wab), "+v"(wef));
      union { unsigned u[4]; bf16x8 v; } flo, fhi;
      flo.u[0] = w01; flo.u[1] = w23; flo.u[2] = w45; flo.u[3] = w67;
      fhi.u[0] = w89; fhi.u[1] = wab; fhi.u[2] = wcd; fhi.u[3] = wef;
      pa[qb][0] = flo.v;
      pa[qb][1] = fhi.v;
    }
    // O += P V   (V chunk = sgrp*4 + ksl*2 + hi, XOR row&7)
    __builtin_amdgcn_s_setprio(1);
#pragma unroll
    for (int ksl = 0; ksl < 2; ++ksl) {
#pragma unroll
      for (int jn = 0; jn < 2; ++jn) {
        int ch = (sgrp * 4 + ksl * 2 + hi) ^ r7;
        bf16x8 vf = *(const bf16x8*)&Vc[((jn * 32 + l31) * 8 + ch) * 8];
        o[0][jn] = __builtin_amdgcn_mfma_f32_32x32x16_bf16(pa[0][ksl], vf, o[0][jn], 0, 0, 0);
        o[1][jn] = __builtin_amdgcn_mfma_f32_32x32x16_bf16(pa[1][ksl], vf, o[1][jn], 0, 0, 0);
      }
    }
    __builtin_amdgcn_s_setprio(0);
  };

  STAGE(0, 0);
  for (int kt = 0; kt < 32; kt += 2) {
    __syncthreads();            // buf0 staged (vmcnt drained); buf1 reads done
    STAGE(1, kt + 1);
    COMPUTE(0);
    __syncthreads();            // buf1 staged; buf0 reads done
    if (kt + 2 < 32) STAGE(0, kt + 2);
    COMPUTE(1);
  }

  // ---- split-K combine via LDS overlay --------------------------------
  __syncthreads();              // all K/V tile reads done -> overlay safe
  float* Op = (float*)smem;     // [qc*2+qb][32 rows][64 hd] = 32KB exact
  const int b = bh >> 4, hh = bh & 15;

#define EPI_WRITE(QB) do {                                                   \
    _Pragma("unroll")                                                        \
    for (int r = 0; r < 16; ++r) {                                           \
      int crow = (r & 3) + 8 * (r >> 2) + 4 * hi;                            \
      float* dst = &Op[((qc * 2 + (QB)) * 32 + crow) * 64 + l31];            \
      dst[0]  = o[QB][0][r];                                                 \
      dst[32] = o[QB][1][r];                                                 \
    }                                                                        \
    float lW = psum[QB] + __shfl_xor(psum[QB], 32);                          \
    if (hi == 0) Lpart[qc][QB][l31] = lW;                                    \
  } while (0)

#define EPI_COMBINE(QB) do {                                                 \
    float lC = psum[QB] + __shfl_xor(psum[QB], 32);                          \
    if (hi == 0) Ls[qc][QB][l31] = 1.0f / (lC + Lpart[qc][QB][l31]);         \
    asm volatile("s_waitcnt lgkmcnt(0)" ::: "memory");                       \
    _Pragma("unroll")                                                        \
    for (int r = 0; r < 16; ++r) {                                           \
      int crow = (r & 3) + 8 * (r >> 2) + 4 * hi;                            \
      float inv = Ls[qc][QB][crow];                                          \
      const float* src = &Op[((qc * 2 + (QB)) * 32 + crow) * 64 + l31];      \
      int qrow = q0blk + qc * 64 + (QB) * 32 + crow;                         \
      float* po = &out[(size_t)(b * SEQ + qrow) * DIM + hh * HD + l31];      \
      po[0]  = (o[QB][0][r] + src[0])  * inv;                                \
      po[32] = (o[QB][1][r] + src[32]) * inv;                                \
    }                                                                        \
  } while (0)

  // sgrp0 writes its qb=1 partial & combines qb=0; sgrp1 mirrors
  if (sgrp == 0) EPI_WRITE(1); else EPI_WRITE(0);
  __syncthreads();
  if (sgrp == 0) EPI_COMBINE(0); else EPI_COMBINE(1);

#undef EPI_WRITE
#undef EPI_COMBINE
}

extern "C" void kernel_launch(void* const* d_in, const int* in_sizes, int n_in,
                              void* d_out, int out_size, void* d_ws, size_t ws_size,
                              hipStream_t stream) {
  const float* x  = (const float*)d_in[0];
  const float* Wq = (const float*)d_in[1];
  const float* bq = (const float*)d_in[2];
  const float* Wk = (const float*)d_in[3];
  const float* bk = (const float*)d_in[4];
  const float* Wv = (const float*)d_in[5];
  const float* bv = (const float*)d_in[6];
  float* out = (float*)d_out;

  unsigned short* ws = (unsigned short*)d_ws;
  const size_t XE = (size_t)BATCH * SEQ * DIM;   // 8388608
  const size_t WE = (size_t)DIM * DIM;           // 1048576
  unsigned short* xb  = ws;
  unsigned short* wqb = xb + XE;
  unsigned short* wkb = wqb + WE;
  unsigned short* wvb = wkb + WE;
  unsigned short* qb  = wvb + WE;
  unsigned short* kb  = qb + XE;
  unsigned short* vb  = kb + XE;

  const int total_groups = (int)(XE / 8 + 3 * (WE / 8));   // 1441792
  cast_all_kernel<<<total_groups / 256, 256, 0, stream>>>(
      x, Wq, Wk, Wv, xb, wqb, wkb, wvb);

  dim3 gg(64, 8, 3);
  gemm_qkv<<<gg, 256, 0, stream>>>(xb, wqb, wkb, wvb, bq, bk, bv, qb, kb, vb);

  dim3 fg(16, BATCH * NH);
  flash_kernel<<<fg, 256, 0, stream>>>(qb, kb, vb, out);
}

// Round 4
// 250.975 us; speedup vs baseline: 2.7977x; 1.0213x over previous
//
#include <hip/hip_runtime.h>

typedef __bf16 bf16x8 __attribute__((ext_vector_type(8)));
typedef float f32x4 __attribute__((ext_vector_type(4)));
typedef float f32x16 __attribute__((ext_vector_type(16)));

#define BATCH 4
#define SEQ   2048
#define DIM   1024
#define NH    16
#define HD    64
#define ECF   0.18033688f   // log2(e)/8 : folds 1/sqrt(64) into exp2

__device__ __forceinline__ unsigned short f2bf(float f) {
  union { float f; unsigned u; } v; v.f = f;
  unsigned u = v.u;
  u += 0x7FFF + ((u >> 16) & 1);   // round-to-nearest-even
  return (unsigned short)(u >> 16);
}

__device__ __forceinline__ void g2lds16(const unsigned short* g, unsigned short* l) {
  __builtin_amdgcn_global_load_lds(
      (const __attribute__((address_space(1))) unsigned int*)g,
      (__attribute__((address_space(3))) unsigned int*)l, 16, 0, 0);
}

// scalar-cast pack (compiler emits v_cvt_pk_bf16_f32; m240: faster than hand asm)
__device__ __forceinline__ unsigned packbf(float a, float b) {
  __bf16 lo = (__bf16)a, hi = (__bf16)b;
  unsigned short ul = __builtin_bit_cast(unsigned short, lo);
  unsigned short uh = __builtin_bit_cast(unsigned short, hi);
  return (unsigned)ul | ((unsigned)uh << 16);
}

// ------------- fused cast fp32 -> bf16 (x, Wq*EC, Wk, Wv) -------------
__global__ __launch_bounds__(256) void cast_all_kernel(
    const float* __restrict__ x,  const float* __restrict__ Wq,
    const float* __restrict__ Wk, const float* __restrict__ Wv,
    unsigned short* __restrict__ xb,  unsigned short* __restrict__ wqb,
    unsigned short* __restrict__ wkb, unsigned short* __restrict__ wvb) {
  const int XG = (BATCH * SEQ * DIM) / 8;   // 1048576
  const int WG = (DIM * DIM) / 8;           // 131072
  int i = blockIdx.x * 256 + threadIdx.x;
  const float* in; unsigned short* out; float sc = 1.0f; int off;
  if (i < XG)               { in = x;  out = xb;  off = i; }
  else if (i < XG + WG)     { in = Wq; out = wqb; off = i - XG; sc = ECF; }
  else if (i < XG + 2 * WG) { in = Wk; out = wkb; off = i - XG - WG; }
  else                      { in = Wv; out = wvb; off = i - XG - 2 * WG; }
  const float4* p = (const float4*)in + (size_t)off * 2;
  float4 a = p[0], b = p[1];
  unsigned short r[8];
  r[0] = f2bf(a.x * sc); r[1] = f2bf(a.y * sc); r[2] = f2bf(a.z * sc); r[3] = f2bf(a.w * sc);
  r[4] = f2bf(b.x * sc); r[5] = f2bf(b.y * sc); r[6] = f2bf(b.z * sc); r[7] = f2bf(b.w * sc);
  *(uint4*)&out[(size_t)off * 8] = *(uint4*)r;
}

// ---------------- fused QKV projection GEMM (unchanged) ---------------
__global__ __launch_bounds__(256) void gemm_qkv(
    const unsigned short* __restrict__ A,
    const unsigned short* __restrict__ Wqp, const unsigned short* __restrict__ Wkp,
    const unsigned short* __restrict__ Wvp,
    const float* __restrict__ bqp, const float* __restrict__ bkp,
    const float* __restrict__ bvp,
    unsigned short* __restrict__ oq, unsigned short* __restrict__ ok,
    unsigned short* __restrict__ ov) {
  __shared__ unsigned short As[128 * 32];
  __shared__ unsigned short Bs[128 * 32];
  const int z = blockIdx.z;
  const unsigned short* W = (z == 0) ? Wqp : (z == 1) ? Wkp : Wvp;
  const float* bias        = (z == 0) ? bqp : (z == 1) ? bkp : bvp;
  unsigned short* outp     = (z == 0) ? oq  : (z == 1) ? ok  : ov;
  const float bsc          = (z == 0) ? ECF : 1.0f;   // bq scaled like Wq
  const int mode = (z == 2) ? 1 : 0;

  const int tid  = threadIdx.x;
  const int wave = tid >> 6;
  const int lane = tid & 63;
  const int lm   = lane & 15;
  const int qd   = lane >> 4;
  const int m0 = blockIdx.x * 128;
  const int n0 = blockIdx.y * 128;
  const int wm = (wave >> 1) * 64;
  const int wn = (wave & 1) * 64;

  const f32x4 zero = {0.f, 0.f, 0.f, 0.f};
  f32x4 acc[4][4];
#pragma unroll
  for (int i = 0; i < 4; ++i)
#pragma unroll
    for (int j = 0; j < 4; ++j) acc[i][j] = zero;

  const int srow = tid >> 2;                               // 0..63
  const int scol = (((tid & 3) ^ ((tid >> 3) & 3))) * 8;   // swizzled source chunk
  const int cs   = (qd ^ ((lm >> 1) & 3)) * 8;             // swizzled read chunk

  for (int kt = 0; kt < DIM; kt += 32) {
    __syncthreads();
    g2lds16(&A[(size_t)(m0 + srow) * DIM + kt + scol],       &As[(size_t)tid * 8]);
    g2lds16(&A[(size_t)(m0 + 64 + srow) * DIM + kt + scol],  &As[2048 + (size_t)tid * 8]);
    g2lds16(&W[(size_t)(n0 + srow) * DIM + kt + scol],       &Bs[(size_t)tid * 8]);
    g2lds16(&W[(size_t)(n0 + 64 + srow) * DIM + kt + scol],  &Bs[2048 + (size_t)tid * 8]);
    __syncthreads();

    bf16x8 af[4], bfr[4];
#pragma unroll
    for (int i = 0; i < 4; ++i) af[i]  = *(const bf16x8*)&As[(wm + i * 16 + lm) * 32 + cs];
#pragma unroll
    for (int j = 0; j < 4; ++j) bfr[j] = *(const bf16x8*)&Bs[(wn + j * 16 + lm) * 32 + cs];
#pragma unroll
    for (int i = 0; i < 4; ++i)
#pragma unroll
      for (int j = 0; j < 4; ++j)
        acc[i][j] = __builtin_amdgcn_mfma_f32_16x16x32_bf16(af[i], bfr[j], acc[i][j], 0, 0, 0);
  }

#pragma unroll
  for (int j = 0; j < 4; ++j) {
    int col = n0 + wn + j * 16 + lm;       // n index
    float bb = bias[col] * bsc;
    int h = col >> 6, hd = col & 63;
#pragma unroll
    for (int i = 0; i < 4; ++i) {
      int rowb = m0 + wm + i * 16 + qd * 4;   // base m index (r=0)
      int b = rowb >> 11, s = rowb & 2047;
      if (mode == 0) {
#pragma unroll
        for (int r = 0; r < 4; ++r) {
          float v = acc[i][j][r] + bb;
          outp[((size_t)(b * NH + h) * SEQ + (s + r)) * HD + hd] = f2bf(v);
        }
      } else {
        unsigned short pk[4];
#pragma unroll
        for (int r = 0; r < 4; ++r) pk[r] = f2bf(acc[i][j][r] + bb);
        size_t idx = ((size_t)(b * NH + h) * HD + hd) * SEQ + s;
        *(uint2*)&outp[idx] = *(uint2*)pk;
      }
    }
  }
}

// ---------------- flash attention: 4 waves x 64 q-rows, 32x32 MFMA ----
// R9 = R6 (proven 96us) + de-phase-locking. R6 post-mortem: per-CU pipe
// demands (MFMA 2048 / VALU 2200 / TRANS 2048 / DS 1536 cyc per tile-step)
// SUM to the measured 7200 -> pipes ~92% serialized: all waves march
// through identical QKT->exp->PV phases, barrier-aligned. R7/R8 (occupancy)
// regressed. Fix here:
//  * in-tile software pipeline: QKT(A), QKT(B) independent up-front; then
//    exp/pack(A) [interleaves w/ QKT(B)], PV(A) [interleaves w/ exp/pack(B)],
//    PV(B). Every VALU burst has adjacent independent MFMA work.
//  * wave stagger: odd waves process halves in opposite order (kbA = w&1)
//    -> at any instant half the waves are MFMA-phase, half VALU-phase.
//  * T5 setprio around MFMA clusters (pays once waves have role diversity).
__global__ __launch_bounds__(256, 2) void flash_kernel(
    const unsigned short* __restrict__ Qp, const unsigned short* __restrict__ Kp,
    const unsigned short* __restrict__ Vp, float* __restrict__ out) {
  __shared__ __align__(16) unsigned short Ks[2][64 * 64];  // [buf][key][d] swizzled
  __shared__ __align__(16) unsigned short Vs[2][64 * 64];  // [buf][hd][key] swizzled
  __shared__ float Ls[4][2][32];

  const int tid  = threadIdx.x;   // 0..255
  const int w    = tid >> 6;      // wave 0..3
  const int wpar = w & 1;         // stagger parity
  const int lane = tid & 63;
  const int l31  = lane & 31;
  const int hi   = lane >> 5;
  const int bh   = blockIdx.y;
  const int wq0  = blockIdx.x * 256 + w * 64;

  const unsigned short* Qb = Qp + (size_t)bh * (SEQ * HD);
  const unsigned short* Kb = Kp + (size_t)bh * (SEQ * HD);
  const unsigned short* Vb = Vp + (size_t)bh * (HD * SEQ);

  // Q in registers: 64 rows/wave = 2 row-blocks x 4 d-blocks
  bf16x8 qf[2][4];
#pragma unroll
  for (int qb = 0; qb < 2; ++qb)
#pragma unroll
    for (int db = 0; db < 4; ++db)
      qf[qb][db] = *(const bf16x8*)&Qb[(size_t)(wq0 + qb * 32 + l31) * HD + db * 16 + hi * 8];

  f32x16 o[2][2];
#pragma unroll
  for (int qb = 0; qb < 2; ++qb)
#pragma unroll
    for (int jn = 0; jn < 2; ++jn)
#pragma unroll
      for (int r = 0; r < 16; ++r) o[qb][jn][r] = 0.f;
  float psum[2] = {0.f, 0.f};

  // staging: 512 chunks per tensor; thread t fills chunks t, t+256 (linear LDS
  // dest, source chunk pre-swizzled: sc = pos ^ (row&7))
  const int c0 = tid, c1 = tid + 256;
  const int kr0 = c0 >> 3, kp0 = ((c0 & 7) ^ (kr0 & 7)) * 8;
  const int kr1 = c1 >> 3, kp1 = ((c1 & 7) ^ (kr1 & 7)) * 8;
  const int r7 = l31 & 7;   // read-side swizzle key (row = *x32 + l31)

  auto STAGE = [&](int buf, int k0) {
    g2lds16(&Kb[(size_t)(k0 + kr0) * HD + kp0], &Ks[buf][c0 * 8]);
    g2lds16(&Kb[(size_t)(k0 + kr1) * HD + kp1], &Ks[buf][c1 * 8]);
    g2lds16(&Vb[(size_t)kr0 * SEQ + k0 + kp0],  &Vs[buf][c0 * 8]);
    g2lds16(&Vb[(size_t)kr1 * SEQ + k0 + kp1],  &Vs[buf][c1 * 8]);
  };

  STAGE(0, 0);
  int cur = 0;
  for (int kt = 0; kt < SEQ / 64; ++kt) {
    __syncthreads();   // drains vmcnt -> buf[cur] staged; prev reads of buf[cur^1] done
    if (kt + 1 < SEQ / 64) STAGE(cur ^ 1, (kt + 1) * 64);

    const unsigned short* Kc = &Ks[cur][0];
    const unsigned short* Vc = &Vs[cur][0];

    const int kbA = wpar;        // this wave's first 32-key half
    const int kbB = wpar ^ 1;

    // ---- QK^T for both halves (independent MFMA chains) ----
    f32x16 sA0 = {0,0,0,0,0,0,0,0,0,0,0,0,0,0,0,0};
    f32x16 sA1 = {0,0,0,0,0,0,0,0,0,0,0,0,0,0,0,0};
    f32x16 sB0 = {0,0,0,0,0,0,0,0,0,0,0,0,0,0,0,0};
    f32x16 sB1 = {0,0,0,0,0,0,0,0,0,0,0,0,0,0,0,0};
    __builtin_amdgcn_s_setprio(1);
#pragma unroll
    for (int db = 0; db < 4; ++db) {
      int ch = (db * 2 + hi) ^ r7;
      bf16x8 kf = *(const bf16x8*)&Kc[((kbA * 32 + l31) * 8 + ch) * 8];
      sA0 = __builtin_amdgcn_mfma_f32_32x32x16_bf16(kf, qf[0][db], sA0, 0, 0, 0);
      sA1 = __builtin_amdgcn_mfma_f32_32x32x16_bf16(kf, qf[1][db], sA1, 0, 0, 0);
    }
    __builtin_amdgcn_s_setprio(0);
#pragma unroll
    for (int db = 0; db < 4; ++db) {
      int ch = (db * 2 + hi) ^ r7;
      bf16x8 kf = *(const bf16x8*)&Kc[((kbB * 32 + l31) * 8 + ch) * 8];
      sB0 = __builtin_amdgcn_mfma_f32_32x32x16_bf16(kf, qf[0][db], sB0, 0, 0, 0);
      sB1 = __builtin_amdgcn_mfma_f32_32x32x16_bf16(kf, qf[1][db], sB1, 0, 0, 0);
    }

    // ---- exp/pack(A): schedulable against QKT(B) MFMAs above ----
    bf16x8 paA[2][2], paB[2][2];
#define EXPPACK(SQ0, SQ1, PA) do {                                            \
    _Pragma("unroll")                                                         \
    for (int qb = 0; qb < 2; ++qb) {                                          \
      const f32x16 s = qb ? (SQ1) : (SQ0);                                    \
      float p[16];                                                            \
      _Pragma("unroll")                                                       \
      for (int r = 0; r < 16; ++r) p[r] = __builtin_amdgcn_exp2f(s[r]);       \
      psum[qb] += ((p[0] + p[1]) + (p[2] + p[3])) + ((p[4] + p[5]) + (p[6] + p[7]))  \
                + ((p[8] + p[9]) + (p[10] + p[11])) + ((p[12] + p[13]) + (p[14] + p[15])); \
      unsigned w01 = packbf(p[0],  p[1]),  w23 = packbf(p[2],  p[3]);         \
      unsigned w45 = packbf(p[4],  p[5]),  w67 = packbf(p[6],  p[7]);         \
      unsigned w89 = packbf(p[8],  p[9]),  wab = packbf(p[10], p[11]);        \
      unsigned wcd = packbf(p[12], p[13]), wef = packbf(p[14], p[15]);        \
      asm volatile("v_permlane32_swap_b32 %0, %1" : "+v"(w01), "+v"(w45));    \
      asm volatile("v_permlane32_swap_b32 %0, %1" : "+v"(w23), "+v"(w67));    \
      asm volatile("v_permlane32_swap_b32 %0, %1" : "+v"(w89), "+v"(wcd));    \
      asm volatile("v_permlane32_swap_b32 %0, %1" : "+v"(wab), "+v"(wef));    \
      union { unsigned u[4]; bf16x8 v; } flo, fhi;                            \
      flo.u[0] = w01; flo.u[1] = w23; flo.u[2] = w45; flo.u[3] = w67;         \
      fhi.u[0] = w89; fhi.u[1] = wab; fhi.u[2] = wcd; fhi.u[3] = wef;         \
      (PA)[qb][0] = flo.v;                                                    \
      (PA)[qb][1] = fhi.v;                                                    \
    }                                                                         \
  } while (0)

#define PVHALF(KB, PA) do {                                                   \
    _Pragma("unroll")                                                         \
    for (int ksl = 0; ksl < 2; ++ksl) {                                       \
      int ks = (KB) * 2 + ksl;                                                \
      _Pragma("unroll")                                                       \
      for (int jn = 0; jn < 2; ++jn) {                                        \
        int ch = (ks * 2 + hi) ^ r7;                                          \
        bf16x8 vf = *(const bf16x8*)&Vc[((jn * 32 + l31) * 8 + ch) * 8];      \
        o[0][jn] = __builtin_amdgcn_mfma_f32_32x32x16_bf16((PA)[0][ksl], vf, o[0][jn], 0, 0, 0); \
        o[1][jn] = __builtin_amdgcn_mfma_f32_32x32x16_bf16((PA)[1][ksl], vf, o[1][jn], 0, 0, 0); \
      }                                                                       \
    }                                                                         \
  } while (0)

    EXPPACK(sA0, sA1, paA);
    // ---- PV(A) MFMAs ∥ exp/pack(B) VALU ----
    __builtin_amdgcn_s_setprio(1);
    PVHALF(kbA, paA);
    __builtin_amdgcn_s_setprio(0);
    EXPPACK(sB0, sB1, paB);
    __builtin_amdgcn_s_setprio(1);
    PVHALF(kbB, paB);
    __builtin_amdgcn_s_setprio(0);

#undef EXPPACK
#undef PVHALF
    cur ^= 1;
  }

  // final row-sum reduce (over the two key-halves per lane pair) & normalize
#pragma unroll
  for (int qb = 0; qb < 2; ++qb) {
    float l = psum[qb] + __shfl_xor(psum[qb], 32);
    if (hi == 0) Ls[w][qb][l31] = 1.0f / l;
  }
  asm volatile("s_waitcnt lgkmcnt(0)" ::: "memory");   // same-wave LDS RAW

  const int b = bh >> 4, hh = bh & 15;
#pragma unroll
  for (int qb = 0; qb < 2; ++qb)
#pragma unroll
    for (int r = 0; r < 16; ++r) {
      int crow = (r & 3) + 8 * (r >> 2) + 4 * hi;
      float inv = Ls[w][qb][crow];
      int qrow = wq0 + qb * 32 + crow;
      float* po = &out[(size_t)(b * SEQ + qrow) * DIM + hh * HD + l31];
      po[0]  = o[qb][0][r] * inv;
      po[32] = o[qb][1][r] * inv;
    }
}

extern "C" void kernel_launch(void* const* d_in, const int* in_sizes, int n_in,
                              void* d_out, int out_size, void* d_ws, size_t ws_size,
                              hipStream_t stream) {
  const float* x  = (const float*)d_in[0];
  const float* Wq = (const float*)d_in[1];
  const float* bq = (const float*)d_in[2];
  const float* Wk = (const float*)d_in[3];
  const float* bk = (const float*)d_in[4];
  const float* Wv = (const float*)d_in[5];
  const float* bv = (const float*)d_in[6];
  float* out = (float*)d_out;

  unsigned short* ws = (unsigned short*)d_ws;
  const size_t XE = (size_t)BATCH * SEQ * DIM;   // 8388608
  const size_t WE = (size_t)DIM * DIM;           // 1048576
  unsigned short* xb  = ws;
  unsigned short* wqb = xb + XE;
  unsigned short* wkb = wqb + WE;
  unsigned short* wvb = wkb + WE;
  unsigned short* qb  = wvb + WE;
  unsigned short* kb  = qb + XE;
  unsigned short* vb  = kb + XE;

  const int total_groups = (int)(XE / 8 + 3 * (WE / 8));   // 1441792
  cast_all_kernel<<<total_groups / 256, 256, 0, stream>>>(
      x, Wq, Wk, Wv, xb, wqb, wkb, wvb);

  dim3 gg(64, 8, 3);
  gemm_qkv<<<gg, 256, 0, stream>>>(xb, wqb, wkb, wvb, bq, bk, bv, qb, kb, vb);

  dim3 fg(SEQ / 256, BATCH * NH);
  flash_kernel<<<fg, 256, 0, stream>>>(qb, kb, vb, out);
}

// Round 5
// 247.845 us; speedup vs baseline: 2.8330x; 1.0126x over previous
//
#include <hip/hip_runtime.h>

typedef __bf16 bf16x8 __attribute__((ext_vector_type(8)));
typedef float f32x4 __attribute__((ext_vector_type(4)));
typedef float f32x16 __attribute__((ext_vector_type(16)));

#define BATCH 4
#define SEQ   2048
#define DIM   1024
#define NH    16
#define HD    64
#define ECF   0.18033688f   // log2(e)/8 : folds 1/sqrt(64) into exp2

__device__ __forceinline__ unsigned short f2bf(float f) {
  union { float f; unsigned u; } v; v.f = f;
  unsigned u = v.u;
  u += 0x7FFF + ((u >> 16) & 1);   // round-to-nearest-even
  return (unsigned short)(u >> 16);
}

__device__ __forceinline__ void g2lds16(const unsigned short* g, unsigned short* l) {
  __builtin_amdgcn_global_load_lds(
      (const __attribute__((address_space(1))) unsigned int*)g,
      (__attribute__((address_space(3))) unsigned int*)l, 16, 0, 0);
}

// scalar-cast pack (compiler emits v_cvt_pk_bf16_f32; m240: faster than hand asm)
__device__ __forceinline__ unsigned packbf(float a, float b) {
  __bf16 lo = (__bf16)a, hi = (__bf16)b;
  unsigned short ul = __builtin_bit_cast(unsigned short, lo);
  unsigned short uh = __builtin_bit_cast(unsigned short, hi);
  return (unsigned)ul | ((unsigned)uh << 16);
}

// ------------- fused cast fp32 -> bf16 (x, Wq*EC, Wk, Wv) -------------
__global__ __launch_bounds__(256) void cast_all_kernel(
    const float* __restrict__ x,  const float* __restrict__ Wq,
    const float* __restrict__ Wk, const float* __restrict__ Wv,
    unsigned short* __restrict__ xb,  unsigned short* __restrict__ wqb,
    unsigned short* __restrict__ wkb, unsigned short* __restrict__ wvb) {
  const int XG = (BATCH * SEQ * DIM) / 8;   // 1048576
  const int WG = (DIM * DIM) / 8;           // 131072
  int i = blockIdx.x * 256 + threadIdx.x;
  const float* in; unsigned short* out; float sc = 1.0f; int off;
  if (i < XG)               { in = x;  out = xb;  off = i; }
  else if (i < XG + WG)     { in = Wq; out = wqb; off = i - XG; sc = ECF; }
  else if (i < XG + 2 * WG) { in = Wk; out = wkb; off = i - XG - WG; }
  else                      { in = Wv; out = wvb; off = i - XG - 2 * WG; }
  const float4* p = (const float4*)in + (size_t)off * 2;
  float4 a = p[0], b = p[1];
  unsigned short r[8];
  r[0] = f2bf(a.x * sc); r[1] = f2bf(a.y * sc); r[2] = f2bf(a.z * sc); r[3] = f2bf(a.w * sc);
  r[4] = f2bf(b.x * sc); r[5] = f2bf(b.y * sc); r[6] = f2bf(b.z * sc); r[7] = f2bf(b.w * sc);
  *(uint4*)&out[(size_t)off * 8] = *(uint4*)r;
}

// ---------------- fused QKV projection GEMM (unchanged) ---------------
__global__ __launch_bounds__(256) void gemm_qkv(
    const unsigned short* __restrict__ A,
    const unsigned short* __restrict__ Wqp, const unsigned short* __restrict__ Wkp,
    const unsigned short* __restrict__ Wvp,
    const float* __restrict__ bqp, const float* __restrict__ bkp,
    const float* __restrict__ bvp,
    unsigned short* __restrict__ oq, unsigned short* __restrict__ ok,
    unsigned short* __restrict__ ov) {
  __shared__ unsigned short As[128 * 32];
  __shared__ unsigned short Bs[128 * 32];
  const int z = blockIdx.z;
  const unsigned short* W = (z == 0) ? Wqp : (z == 1) ? Wkp : Wvp;
  const float* bias        = (z == 0) ? bqp : (z == 1) ? bkp : bvp;
  unsigned short* outp     = (z == 0) ? oq  : (z == 1) ? ok  : ov;
  const float bsc          = (z == 0) ? ECF : 1.0f;   // bq scaled like Wq
  const int mode = (z == 2) ? 1 : 0;

  const int tid  = threadIdx.x;
  const int wave = tid >> 6;
  const int lane = tid & 63;
  const int lm   = lane & 15;
  const int qd   = lane >> 4;
  const int m0 = blockIdx.x * 128;
  const int n0 = blockIdx.y * 128;
  const int wm = (wave >> 1) * 64;
  const int wn = (wave & 1) * 64;

  const f32x4 zero = {0.f, 0.f, 0.f, 0.f};
  f32x4 acc[4][4];
#pragma unroll
  for (int i = 0; i < 4; ++i)
#pragma unroll
    for (int j = 0; j < 4; ++j) acc[i][j] = zero;

  const int srow = tid >> 2;                               // 0..63
  const int scol = (((tid & 3) ^ ((tid >> 3) & 3))) * 8;   // swizzled source chunk
  const int cs   = (qd ^ ((lm >> 1) & 3)) * 8;             // swizzled read chunk

  for (int kt = 0; kt < DIM; kt += 32) {
    __syncthreads();
    g2lds16(&A[(size_t)(m0 + srow) * DIM + kt + scol],       &As[(size_t)tid * 8]);
    g2lds16(&A[(size_t)(m0 + 64 + srow) * DIM + kt + scol],  &As[2048 + (size_t)tid * 8]);
    g2lds16(&W[(size_t)(n0 + srow) * DIM + kt + scol],       &Bs[(size_t)tid * 8]);
    g2lds16(&W[(size_t)(n0 + 64 + srow) * DIM + kt + scol],  &Bs[2048 + (size_t)tid * 8]);
    __syncthreads();

    bf16x8 af[4], bfr[4];
#pragma unroll
    for (int i = 0; i < 4; ++i) af[i]  = *(const bf16x8*)&As[(wm + i * 16 + lm) * 32 + cs];
#pragma unroll
    for (int j = 0; j < 4; ++j) bfr[j] = *(const bf16x8*)&Bs[(wn + j * 16 + lm) * 32 + cs];
#pragma unroll
    for (int i = 0; i < 4; ++i)
#pragma unroll
      for (int j = 0; j < 4; ++j)
        acc[i][j] = __builtin_amdgcn_mfma_f32_16x16x32_bf16(af[i], bfr[j], acc[i][j], 0, 0, 0);
  }

#pragma unroll
  for (int j = 0; j < 4; ++j) {
    int col = n0 + wn + j * 16 + lm;       // n index
    float bb = bias[col] * bsc;
    int h = col >> 6, hd = col & 63;
#pragma unroll
    for (int i = 0; i < 4; ++i) {
      int rowb = m0 + wm + i * 16 + qd * 4;   // base m index (r=0)
      int b = rowb >> 11, s = rowb & 2047;
      if (mode == 0) {
#pragma unroll
        for (int r = 0; r < 4; ++r) {
          float v = acc[i][j][r] + bb;
          outp[((size_t)(b * NH + h) * SEQ + (s + r)) * HD + hd] = f2bf(v);
        }
      } else {
        unsigned short pk[4];
#pragma unroll
        for (int r = 0; r < 4; ++r) pk[r] = f2bf(acc[i][j][r] + bb);
        size_t idx = ((size_t)(b * NH + h) * HD + hd) * SEQ + s;
        *(uint2*)&outp[idx] = *(uint2*)pk;
      }
    }
  }
}

// ---- flash attention: 4 waves x 64 q-rows, 4-phase counted-vmcnt ----
// R10: R6 layout (proven 96us) + m201/m218-style schedule. R6's single
// __syncthreads/tile compiles to a full vmcnt(0) drain -> all waves stall
// together then march phase-locked (m233's "2-phase stall" regime; R9
// proved source-order shuffling can't fix it). Here:
//  * 64-key tile split into 4 phases, raw s_barrier pairs per phase:
//    {ds_read frags | issue 1 next-next-tile gload} BAR {setprio MFMA} BAR
//    exp/pack(kb0) in P2, exp/pack(kb1) in P3 -> VALU bursts adjacent to
//    other waves' MFMA phases (role diversity T5 can arbitrate, m218b).
//  * TRIPLE-buffered K/V LDS (48KB), stage 2 tiles ahead, ONE
//    s_waitcnt vmcnt(4) per tile (4 loads/thread/tile in flight across
//    barriers -- T4 counted-vmcnt, never 0 in steady state).
//  * ds_read->MFMA deps left to compiler lgkm tracking (m97: near-optimal;
//    avoids rule-18 inline-asm hazard).
__global__ __launch_bounds__(256, 2) void flash_kernel(
    const unsigned short* __restrict__ Qp, const unsigned short* __restrict__ Kp,
    const unsigned short* __restrict__ Vp, float* __restrict__ out) {
  __shared__ __align__(16) unsigned short Ks[3][64 * 64];  // [buf][key][d] swizzled
  __shared__ __align__(16) unsigned short Vs[3][64 * 64];  // [buf][hd][key] swizzled
  __shared__ float Ls[4][2][32];

  const int tid  = threadIdx.x;   // 0..255
  const int w    = tid >> 6;      // wave 0..3
  const int lane = tid & 63;
  const int l31  = lane & 31;
  const int hi   = lane >> 5;
  const int bh   = blockIdx.y;
  const int wq0  = blockIdx.x * 256 + w * 64;

  const unsigned short* Qb = Qp + (size_t)bh * (SEQ * HD);
  const unsigned short* Kb = Kp + (size_t)bh * (SEQ * HD);
  const unsigned short* Vb = Vp + (size_t)bh * (HD * SEQ);

  // Q in registers: 64 rows/wave = 2 row-blocks x 4 d-blocks
  bf16x8 qf[2][4];
#pragma unroll
  for (int qb = 0; qb < 2; ++qb)
#pragma unroll
    for (int db = 0; db < 4; ++db)
      qf[qb][db] = *(const bf16x8*)&Qb[(size_t)(wq0 + qb * 32 + l31) * HD + db * 16 + hi * 8];

  f32x16 o[2][2];
#pragma unroll
  for (int qb = 0; qb < 2; ++qb)
#pragma unroll
    for (int jn = 0; jn < 2; ++jn)
#pragma unroll
      for (int r = 0; r < 16; ++r) o[qb][jn][r] = 0.f;
  float psum[2] = {0.f, 0.f};

  // staging: 512 chunks per tensor; thread t fills chunks t, t+256 (linear LDS
  // dest, source chunk pre-swizzled: sc = pos ^ (row&7))
  const int c0 = tid, c1 = tid + 256;
  const int kr0 = c0 >> 3, kp0 = ((c0 & 7) ^ (kr0 & 7)) * 8;
  const int kr1 = c1 >> 3, kp1 = ((c1 & 7) ^ (kr1 & 7)) * 8;
  const int r7 = l31 & 7;   // read-side swizzle key (row = *x32 + l31)

#define SK0(buf, k0) g2lds16(&Kb[(size_t)((k0) + kr0) * HD + kp0], &Ks[buf][c0 * 8])
#define SK1(buf, k0) g2lds16(&Kb[(size_t)((k0) + kr1) * HD + kp1], &Ks[buf][c1 * 8])
#define SV0(buf, k0) g2lds16(&Vb[(size_t)kr0 * SEQ + (k0) + kp0],  &Vs[buf][c0 * 8])
#define SV1(buf, k0) g2lds16(&Vb[(size_t)kr1 * SEQ + (k0) + kp1],  &Vs[buf][c1 * 8])
#define BAR() asm volatile("s_barrier" ::: "memory")

#define EXPPACK(SQ0, SQ1, PA) do {                                            \
    _Pragma("unroll")                                                         \
    for (int qb = 0; qb < 2; ++qb) {                                          \
      const f32x16 s = qb ? (SQ1) : (SQ0);                                    \
      float p[16];                                                            \
      _Pragma("unroll")                                                       \
      for (int r = 0; r < 16; ++r) p[r] = __builtin_amdgcn_exp2f(s[r]);       \
      psum[qb] += ((p[0] + p[1]) + (p[2] + p[3])) + ((p[4] + p[5]) + (p[6] + p[7]))  \
                + ((p[8] + p[9]) + (p[10] + p[11])) + ((p[12] + p[13]) + (p[14] + p[15])); \
      unsigned w01 = packbf(p[0],  p[1]),  w23 = packbf(p[2],  p[3]);         \
      unsigned w45 = packbf(p[4],  p[5]),  w67 = packbf(p[6],  p[7]);         \
      unsigned w89 = packbf(p[8],  p[9]),  wab = packbf(p[10], p[11]);        \
      unsigned wcd = packbf(p[12], p[13]), wef = packbf(p[14], p[15]);        \
      asm volatile("v_permlane32_swap_b32 %0, %1" : "+v"(w01), "+v"(w45));    \
      asm volatile("v_permlane32_swap_b32 %0, %1" : "+v"(w23), "+v"(w67));    \
      asm volatile("v_permlane32_swap_b32 %0, %1" : "+v"(w89), "+v"(wcd));    \
      asm volatile("v_permlane32_swap_b32 %0, %1" : "+v"(wab), "+v"(wef));    \
      union { unsigned u[4]; bf16x8 v; } flo, fhi;                            \
      flo.u[0] = w01; flo.u[1] = w23; flo.u[2] = w45; flo.u[3] = w67;         \
      fhi.u[0] = w89; fhi.u[1] = wab; fhi.u[2] = wcd; fhi.u[3] = wef;         \
      (PA)[qb][0] = flo.v;                                                    \
      (PA)[qb][1] = fhi.v;                                                    \
    }                                                                         \
  } while (0)

  // prologue: tiles 0,1 fully staged; wait tile0 (oldest 4) landed
  SK0(0, 0);  SK1(0, 0);  SV0(0, 0);  SV1(0, 0);
  SK0(1, 64); SK1(1, 64); SV0(1, 64); SV1(1, 64);
  asm volatile("s_waitcnt vmcnt(4)" ::: "memory");
  BAR();

  for (int kt = 0; kt < 32; ++kt) {
    const int cur = kt % 3;
    const int nb  = (kt + 2) % 3;
    const bool st = (kt + 2) < 32;
    const int k2  = (kt + 2) * 64;
    const unsigned short* Kc = &Ks[cur][0];
    const unsigned short* Vc = &Vs[cur][0];

    // ---- P1: K kb0 frags + stage K0(next2) | QK^T kb0 ----
    f32x16 sA0 = {0,0,0,0,0,0,0,0,0,0,0,0,0,0,0,0};
    f32x16 sA1 = {0,0,0,0,0,0,0,0,0,0,0,0,0,0,0,0};
    {
      bf16x8 kf[4];
#pragma unroll
      for (int db = 0; db < 4; ++db)
        kf[db] = *(const bf16x8*)&Kc[((0 * 32 + l31) * 8 + ((db * 2 + hi) ^ r7)) * 8];
      if (st) SK0(nb, k2);
      BAR();
      __builtin_amdgcn_s_setprio(1);
#pragma unroll
      for (int db = 0; db < 4; ++db) {
        sA0 = __builtin_amdgcn_mfma_f32_32x32x16_bf16(kf[db], qf[0][db], sA0, 0, 0, 0);
        sA1 = __builtin_amdgcn_mfma_f32_32x32x16_bf16(kf[db], qf[1][db], sA1, 0, 0, 0);
      }
      __builtin_amdgcn_s_setprio(0);
      BAR();
    }

    // ---- P2: K kb1 frags + stage K1 + exp/pack(A) | QK^T kb1 ----
    f32x16 sB0 = {0,0,0,0,0,0,0,0,0,0,0,0,0,0,0,0};
    f32x16 sB1 = {0,0,0,0,0,0,0,0,0,0,0,0,0,0,0,0};
    bf16x8 paA[2][2], paB[2][2];
    {
      bf16x8 kf[4];
#pragma unroll
      for (int db = 0; db < 4; ++db)
        kf[db] = *(const bf16x8*)&Kc[((1 * 32 + l31) * 8 + ((db * 2 + hi) ^ r7)) * 8];
      if (st) SK1(nb, k2);
      EXPPACK(sA0, sA1, paA);
      BAR();
      __builtin_amdgcn_s_setprio(1);
#pragma unroll
      for (int db = 0; db < 4; ++db) {
        sB0 = __builtin_amdgcn_mfma_f32_32x32x16_bf16(kf[db], qf[0][db], sB0, 0, 0, 0);
        sB1 = __builtin_amdgcn_mfma_f32_32x32x16_bf16(kf[db], qf[1][db], sB1, 0, 0, 0);
      }
      __builtin_amdgcn_s_setprio(0);
      BAR();
    }

    // ---- P3: V ks0,1 frags + stage V0 + exp/pack(B) | PV kb0 ----
    {
      bf16x8 vf[2][2];
#pragma unroll
      for (int ksl = 0; ksl < 2; ++ksl)
#pragma unroll
        for (int jn = 0; jn < 2; ++jn)
          vf[ksl][jn] = *(const bf16x8*)&Vc[((jn * 32 + l31) * 8 + ((ksl * 2 + hi) ^ r7)) * 8];
      if (st) SV0(nb, k2);
      EXPPACK(sB0, sB1, paB);
      BAR();
      __builtin_amdgcn_s_setprio(1);
#pragma unroll
      for (int ksl = 0; ksl < 2; ++ksl)
#pragma unroll
        for (int jn = 0; jn < 2; ++jn) {
          o[0][jn] = __builtin_amdgcn_mfma_f32_32x32x16_bf16(paA[0][ksl], vf[ksl][jn], o[0][jn], 0, 0, 0);
          o[1][jn] = __builtin_amdgcn_mfma_f32_32x32x16_bf16(paA[1][ksl], vf[ksl][jn], o[1][jn], 0, 0, 0);
        }
      __builtin_amdgcn_s_setprio(0);
      BAR();
    }

    // ---- P4: V ks2,3 frags + stage V1 | PV kb1 ; counted vmcnt ----
    {
      bf16x8 vf[2][2];
#pragma unroll
      for (int ksl = 0; ksl < 2; ++ksl)
#pragma unroll
        for (int jn = 0; jn < 2; ++jn)
          vf[ksl][jn] = *(const bf16x8*)&Vc[((jn * 32 + l31) * 8 + (((2 + ksl) * 2 + hi) ^ r7)) * 8];
      if (st) SV1(nb, k2);
      BAR();
      __builtin_amdgcn_s_setprio(1);
#pragma unroll
      for (int ksl = 0; ksl < 2; ++ksl)
#pragma unroll
        for (int jn = 0; jn < 2; ++jn) {
          o[0][jn] = __builtin_amdgcn_mfma_f32_32x32x16_bf16(paB[0][ksl], vf[ksl][jn], o[0][jn], 0, 0, 0);
          o[1][jn] = __builtin_amdgcn_mfma_f32_32x32x16_bf16(paB[1][ksl], vf[ksl][jn], o[1][jn], 0, 0, 0);
        }
      __builtin_amdgcn_s_setprio(0);
      // drain oldest 4 (next tile's buffer); keep this tile's 4 in flight
      if (st) asm volatile("s_waitcnt vmcnt(4)" ::: "memory");
      else    asm volatile("s_waitcnt vmcnt(0)" ::: "memory");
      BAR();
    }
  }

  // final row-sum reduce (over the two key-halves per lane pair) & normalize
#pragma unroll
  for (int qb = 0; qb < 2; ++qb) {
    float l = psum[qb] + __shfl_xor(psum[qb], 32);
    if (hi == 0) Ls[w][qb][l31] = 1.0f / l;
  }
  asm volatile("s_waitcnt lgkmcnt(0)" ::: "memory");   // same-wave LDS RAW

  const int b = bh >> 4, hh = bh & 15;
#pragma unroll
  for (int qb = 0; qb < 2; ++qb)
#pragma unroll
    for (int r = 0; r < 16; ++r) {
      int crow = (r & 3) + 8 * (r >> 2) + 4 * hi;
      float inv = Ls[w][qb][crow];
      int qrow = wq0 + qb * 32 + crow;
      float* po = &out[(size_t)(b * SEQ + qrow) * DIM + hh * HD + l31];
      po[0]  = o[qb][0][r] * inv;
      po[32] = o[qb][1][r] * inv;
    }
#undef SK0
#undef SK1
#undef SV0
#undef SV1
#undef BAR
#undef EXPPACK
}

extern "C" void kernel_launch(void* const* d_in, const int* in_sizes, int n_in,
                              void* d_out, int out_size, void* d_ws, size_t ws_size,
                              hipStream_t stream) {
  const float* x  = (const float*)d_in[0];
  const float* Wq = (const float*)d_in[1];
  const float* bq = (const float*)d_in[2];
  const float* Wk = (const float*)d_in[3];
  const float* bk = (const float*)d_in[4];
  const float* Wv = (const float*)d_in[5];
  const float* bv = (const float*)d_in[6];
  float* out = (float*)d_out;

  unsigned short* ws = (unsigned short*)d_ws;
  const size_t XE = (size_t)BATCH * SEQ * DIM;   // 8388608
  const size_t WE = (size_t)DIM * DIM;           // 1048576
  unsigned short* xb  = ws;
  unsigned short* wqb = xb + XE;
  unsigned short* wkb = wqb + WE;
  unsigned short* wvb = wkb + WE;
  unsigned short* qb  = wvb + WE;
  unsigned short* kb  = qb + XE;
  unsigned short* vb  = kb + XE;

  const int total_groups = (int)(XE / 8 + 3 * (WE / 8));   // 1441792
  cast_all_kernel<<<total_groups / 256, 256, 0, stream>>>(
      x, Wq, Wk, Wv, xb, wqb, wkb, wvb);

  dim3 gg(64, 8, 3);
  gemm_qkv<<<gg, 256, 0, stream>>>(xb, wqb, wkb, wvb, bq, bk, bv, qb, kb, vb);

  dim3 fg(SEQ / 256, BATCH * NH);
  flash_kernel<<<fg, 256, 0, stream>>>(qb, kb, vb, out);
}

// Round 6
// 242.611 us; speedup vs baseline: 2.8941x; 1.0216x over previous
//
#include <hip/hip_runtime.h>

typedef __bf16 bf16x8 __attribute__((ext_vector_type(8)));
typedef float f32x4 __attribute__((ext_vector_type(4)));

#define BATCH 4
#define SEQ   2048
#define DIM   1024
#define NH    16
#define HD    64
#define ECF   0.18033688f   // log2(e)/8 : folds 1/sqrt(64) into exp2

__device__ __forceinline__ unsigned short f2bf(float f) {
  union { float f; unsigned u; } v; v.f = f;
  unsigned u = v.u;
  u += 0x7FFF + ((u >> 16) & 1);   // round-to-nearest-even
  return (unsigned short)(u >> 16);
}

__device__ __forceinline__ void g2lds16(const unsigned short* g, unsigned short* l) {
  __builtin_amdgcn_global_load_lds(
      (const __attribute__((address_space(1))) unsigned int*)g,
      (__attribute__((address_space(3))) unsigned int*)l, 16, 0, 0);
}

// ------------- fused cast fp32 -> bf16 (x, Wq*EC, Wk, Wv) -------------
__global__ __launch_bounds__(256) void cast_all_kernel(
    const float* __restrict__ x,  const float* __restrict__ Wq,
    const float* __restrict__ Wk, const float* __restrict__ Wv,
    unsigned short* __restrict__ xb,  unsigned short* __restrict__ wqb,
    unsigned short* __restrict__ wkb, unsigned short* __restrict__ wvb) {
  const int XG = (BATCH * SEQ * DIM) / 8;   // 1048576
  const int WG = (DIM * DIM) / 8;           // 131072
  int i = blockIdx.x * 256 + threadIdx.x;
  const float* in; unsigned short* out; float sc = 1.0f; int off;
  if (i < XG)               { in = x;  out = xb;  off = i; }
  else if (i < XG + WG)     { in = Wq; out = wqb; off = i - XG; sc = ECF; }
  else if (i < XG + 2 * WG) { in = Wk; out = wkb; off = i - XG - WG; }
  else                      { in = Wv; out = wvb; off = i - XG - 2 * WG; }
  const float4* p = (const float4*)in + (size_t)off * 2;
  float4 a = p[0], b = p[1];
  unsigned short r[8];
  r[0] = f2bf(a.x * sc); r[1] = f2bf(a.y * sc); r[2] = f2bf(a.z * sc); r[3] = f2bf(a.w * sc);
  r[4] = f2bf(b.x * sc); r[5] = f2bf(b.y * sc); r[6] = f2bf(b.z * sc); r[7] = f2bf(b.w * sc);
  *(uint4*)&out[(size_t)off * 8] = *(uint4*)r;
}

// -------- fused QKV projection GEMM: 256x128 tile, BK=64, 2-phase -----
// R11: old gemm was the m97-class 2-barrier BK=32 structure (~400 TF here,
// est. ~125us of the 249 total). Rebuilt with the counted-vmcnt schedule
// proven correct in R10's flash (triple-buffer, stage-2-ahead, raw
// s_barrier, ONE vmcnt(6) per K-tile -- never 0 in steady state; T4/m218)
// and phase-split MFMA clusters wrapped in setprio (T5/m218b).
//  * BM=256 BN=128 BK=64, 512 thr = 8 waves (4M x 2N), wave-tile 64x64
//    (epilogue geometry identical to the old kernel).
//  * LDS: 3 bufs x (A 32KB + B 16KB) = 144KB -> 1 block/CU, 8 waves.
//  * 6 gloads/thread/K-tile (4 A + 2 B), issued spread over the 2 phases,
//    staging tile t+2 while computing t; vmcnt(6) at tile end waits tile
//    t+1 only -- t+2's loads stay in flight across the barrier.
//  * row&7 XOR chunk swizzle, both sides (rule 21), same as flash.
__global__ __launch_bounds__(512, 1) void gemm_qkv(
    const unsigned short* __restrict__ A,
    const unsigned short* __restrict__ Wqp, const unsigned short* __restrict__ Wkp,
    const unsigned short* __restrict__ Wvp,
    const float* __restrict__ bqp, const float* __restrict__ bkp,
    const float* __restrict__ bvp,
    unsigned short* __restrict__ oq, unsigned short* __restrict__ ok,
    unsigned short* __restrict__ ov) {
  // per buf (24576 ushorts): A[256][64] | B[128][64]; rows = 128B = 8 chunks
  __shared__ __align__(16) unsigned short sm[3 * 24576];   // 144KB

  const int z = blockIdx.z;
  const unsigned short* W = (z == 0) ? Wqp : (z == 1) ? Wkp : Wvp;
  const float* bias        = (z == 0) ? bqp : (z == 1) ? bkp : bvp;
  unsigned short* outp     = (z == 0) ? oq  : (z == 1) ? ok  : ov;
  const float bsc          = (z == 0) ? ECF : 1.0f;   // bq scaled like Wq
  const int mode = (z == 2) ? 1 : 0;

  const int tid  = threadIdx.x;   // 0..511
  const int w    = tid >> 6;      // wave 0..7
  const int lane = tid & 63;
  const int lm   = lane & 15;
  const int qd   = lane >> 4;
  const int m0 = blockIdx.x * 256;
  const int n0 = blockIdx.y * 128;
  const int wm = (w & 3) * 64;    // 4 M-groups
  const int wn = (w >> 2) * 64;   // 2 N-groups

  const f32x4 zero = {0.f, 0.f, 0.f, 0.f};
  f32x4 acc[4][4];
#pragma unroll
  for (int i = 0; i < 4; ++i)
#pragma unroll
    for (int j = 0; j < 4; ++j) acc[i][j] = zero;

  // staging: thread t covers chunk pos (t&7) of rows r0+64i; LDS dest is
  // linear 16B*tid (wave-uniform base + lane*16 -- g2lds-compliant);
  // global source chunk pre-swizzled ^(row&7)  [row&7 == r0&7 for all i]
  const int r0 = tid >> 3;                       // 0..63
  const int sp = ((tid & 7) ^ (r0 & 7)) * 8;     // swizzled source col (elems)

#define SA(buf, t4, i) g2lds16(&A[(size_t)(m0 + r0 + 64*(i)) * DIM + (t4)*64 + sp], \
                               &sm[(buf)*24576 + (r0 + 64*(i))*64 + (tid & 7)*8])
#define SB(buf, t4, i) g2lds16(&W[(size_t)(n0 + r0 + 64*(i)) * DIM + (t4)*64 + sp], \
                               &sm[(buf)*24576 + 16384 + (r0 + 64*(i))*64 + (tid & 7)*8])
#define BARR() asm volatile("s_barrier" ::: "memory")

  const int rk = lm & 7;   // read-side swizzle key (row = wX + i*16 + lm)

  // prologue: tiles 0,1 fully staged (12 loads); wait tile0's 6 landed
  SA(0, 0, 0); SA(0, 0, 1); SA(0, 0, 2); SA(0, 0, 3); SB(0, 0, 0); SB(0, 0, 1);
  SA(1, 1, 0); SA(1, 1, 1); SA(1, 1, 2); SA(1, 1, 3); SB(1, 1, 0); SB(1, 1, 1);
  asm volatile("s_waitcnt vmcnt(6)" ::: "memory");
  BARR();

  for (int t = 0; t < DIM / 64; ++t) {          // 16 K-tiles
    const int cur = t % 3;
    const int nb  = (t + 2) % 3;
    const bool st = (t + 2) < DIM / 64;
    const unsigned short* Ab = &sm[cur * 24576];
    const unsigned short* Bb = &sm[cur * 24576 + 16384];

    // ---- P1 (kk=0): ds frags | stage 3 A-chunks | BAR | 16 MFMA | BAR --
    {
      bf16x8 af[4], bfr[4];
#pragma unroll
      for (int i = 0; i < 4; ++i)
        af[i]  = *(const bf16x8*)&Ab[(wm + i * 16 + lm) * 64 + ((qd ^ rk) * 8)];
#pragma unroll
      for (int j = 0; j < 4; ++j)
        bfr[j] = *(const bf16x8*)&Bb[(wn + j * 16 + lm) * 64 + ((qd ^ rk) * 8)];
      if (st) { SA(nb, t + 2, 0); SA(nb, t + 2, 1); SA(nb, t + 2, 2); }
      BARR();
      __builtin_amdgcn_s_setprio(1);
#pragma unroll
      for (int i = 0; i < 4; ++i)
#pragma unroll
        for (int j = 0; j < 4; ++j)
          acc[i][j] = __builtin_amdgcn_mfma_f32_16x16x32_bf16(af[i], bfr[j], acc[i][j], 0, 0, 0);
      __builtin_amdgcn_s_setprio(0);
      BARR();
    }

    // ---- P2 (kk=1): ds frags | stage A3+2 B-chunks | BAR | 16 MFMA ----
    {
      bf16x8 af[4], bfr[4];
#pragma unroll
      for (int i = 0; i < 4; ++i)
        af[i]  = *(const bf16x8*)&Ab[(wm + i * 16 + lm) * 64 + (((4 + qd) ^ rk) * 8)];
#pragma unroll
      for (int j = 0; j < 4; ++j)
        bfr[j] = *(const bf16x8*)&Bb[(wn + j * 16 + lm) * 64 + (((4 + qd) ^ rk) * 8)];
      if (st) { SA(nb, t + 2, 3); SB(nb, t + 2, 0); SB(nb, t + 2, 1); }
      BARR();
      __builtin_amdgcn_s_setprio(1);
#pragma unroll
      for (int i = 0; i < 4; ++i)
#pragma unroll
        for (int j = 0; j < 4; ++j)
          acc[i][j] = __builtin_amdgcn_mfma_f32_16x16x32_bf16(af[i], bfr[j], acc[i][j], 0, 0, 0);
      __builtin_amdgcn_s_setprio(0);
      // counted drain: wait tile t+1 landed, keep t+2's 6 loads in flight
      if (st) asm volatile("s_waitcnt vmcnt(6)" ::: "memory");
      else    asm volatile("s_waitcnt vmcnt(0)" ::: "memory");
      BARR();
    }
  }
#undef SA
#undef SB
#undef BARR

  // epilogue identical to the proven 128^2 kernel (same 64x64 wave-tile)
#pragma unroll
  for (int j = 0; j < 4; ++j) {
    int col = n0 + wn + j * 16 + lm;       // n index
    float bb = bias[col] * bsc;
    int h = col >> 6, hd = col & 63;
#pragma unroll
    for (int i = 0; i < 4; ++i) {
      int rowb = m0 + wm + i * 16 + qd * 4;   // base m index (r=0)
      int b = rowb >> 11, s = rowb & 2047;
      if (mode == 0) {
#pragma unroll
        for (int r = 0; r < 4; ++r) {
          float v = acc[i][j][r] + bb;
          outp[((size_t)(b * NH + h) * SEQ + (s + r)) * HD + hd] = f2bf(v);
        }
      } else {
        unsigned short pk[4];
#pragma unroll
        for (int r = 0; r < 4; ++r) pk[r] = f2bf(acc[i][j][r] + bb);
        size_t idx = ((size_t)(b * NH + h) * HD + hd) * SEQ + s;
        *(uint2*)&outp[idx] = *(uint2*)pk;
      }
    }
  }
}

// ---------------- flash attention: 2 waves, 64 q-rows/wave -----------
// Reverted to the best-measured variant (R0, 95.3us). R6-R10 established
// this structure's floor: 2048 waves total caps occupancy at 8 waves/CU,
// per-wave QKT->exp->pack->PV chain serial, schedule restructures (split-K,
// source reorder, 4-phase counted-vmcnt) all neutral-or-worse.
__global__ __launch_bounds__(128, 2) void flash_kernel(
    const unsigned short* __restrict__ Qw, const unsigned short* __restrict__ Kw,
    const unsigned short* __restrict__ Vw, float* __restrict__ out) {
  __shared__ unsigned short Ks2[2 * 64 * 32];   // [hd_half][key][32] swizzled
  __shared__ unsigned short Vs2[2 * 64 * 32];   // [key_half][hd][32] swizzled
  __shared__ unsigned short Ps[128 * 64];       // [qrow][key] chunk-swizzled
  __shared__ float Ls[128];

  const int tid  = threadIdx.x;   // 0..127
  const int w    = tid >> 6;      // wave 0..1
  const int lane = tid & 63;
  const int lm   = lane & 15;
  const int qd   = lane >> 4;
  const int bh   = blockIdx.y;
  const int q0   = blockIdx.x * 128;

  const unsigned short* Qbase = Qw + (size_t)bh * (SEQ * HD);
  const unsigned short* Kbase = Kw + (size_t)bh * (SEQ * HD);
  const unsigned short* Vbase = Vw + (size_t)bh * (HD * SEQ);

  // Q fragments in registers: 64 rows per wave (4 groups of 16)
  bf16x8 qf[4][2];
#pragma unroll
  for (int g = 0; g < 4; ++g)
#pragma unroll
    for (int h = 0; h < 2; ++h)
      qf[g][h] = *(const bf16x8*)&Qbase[(size_t)(q0 + w * 64 + g * 16 + lm) * HD + h * 32 + qd * 8];

  const f32x4 zero = {0.f, 0.f, 0.f, 0.f};
  f32x4 o[4][4];
#pragma unroll
  for (int g = 0; g < 4; ++g)
#pragma unroll
    for (int jn = 0; jn < 4; ++jn) o[g][jn] = zero;
  float psg[4] = {0.f, 0.f, 0.f, 0.f};

  // staging: 256 16B-chunks per tensor-half pair; thread t fills chunks t, t+128
  const int c0 = tid, c1 = tid + 128;
  const int r0 = c0 >> 2, p0s = ((c0 & 3) ^ ((c0 >> 3) & 3)) * 8;
  const int r1 = c1 >> 2, p1s = ((c1 & 3) ^ ((c1 >> 3) & 3)) * 8;

  const int cs  = (qd ^ ((lm >> 1) & 3)) * 8;   // K/V swizzled read chunk
  const int pk_key = lm & 7;                     // Ps swizzle key

  for (int kt = 0; kt < SEQ / 64; ++kt) {
    const int k0 = kt * 64;
    __syncthreads();
    g2lds16(&Kbase[(size_t)(k0 + r0) * HD + p0s],      &Ks2[(size_t)c0 * 8]);
    g2lds16(&Kbase[(size_t)(k0 + r1) * HD + p1s],      &Ks2[(size_t)c1 * 8]);
    g2lds16(&Kbase[(size_t)(k0 + r0) * HD + 32 + p0s], &Ks2[2048 + (size_t)c0 * 8]);
    g2lds16(&Kbase[(size_t)(k0 + r1) * HD + 32 + p1s], &Ks2[2048 + (size_t)c1 * 8]);
    g2lds16(&Vbase[(size_t)r0 * SEQ + k0 + p0s],       &Vs2[(size_t)c0 * 8]);
    g2lds16(&Vbase[(size_t)r1 * SEQ + k0 + p1s],       &Vs2[(size_t)c1 * 8]);
    g2lds16(&Vbase[(size_t)r0 * SEQ + k0 + 32 + p0s],  &Vs2[2048 + (size_t)c0 * 8]);
    g2lds16(&Vbase[(size_t)r1 * SEQ + k0 + 32 + p1s],  &Vs2[2048 + (size_t)c1 * 8]);
    __syncthreads();

    // S^T = K Q^T : rows key=jk*16+qd*4+r, cols qrow=g*16+lm
#pragma unroll
    for (int jk = 0; jk < 4; ++jk) {
      bf16x8 kf0 = *(const bf16x8*)&Ks2[(jk * 16 + lm) * 32 + cs];
      bf16x8 kf1 = *(const bf16x8*)&Ks2[2048 + (jk * 16 + lm) * 32 + cs];
      f32x4 st[4];
#pragma unroll
      for (int g = 0; g < 4; ++g) {
        st[g] = __builtin_amdgcn_mfma_f32_16x16x32_bf16(kf0, qf[g][0], zero, 0, 0, 0);
        st[g] = __builtin_amdgcn_mfma_f32_16x16x32_bf16(kf1, qf[g][1], st[g], 0, 0, 0);
      }
#pragma unroll
      for (int g = 0; g < 4; ++g) {
        float p0 = __builtin_amdgcn_exp2f(st[g][0]);
        float p1 = __builtin_amdgcn_exp2f(st[g][1]);
        float p2 = __builtin_amdgcn_exp2f(st[g][2]);
        float p3 = __builtin_amdgcn_exp2f(st[g][3]);
        psg[g] += (p0 + p1) + (p2 + p3);
        uint2 pk;
        pk.x = __builtin_amdgcn_perm(__float_as_uint(p1), __float_as_uint(p0), 0x07060302);
        pk.y = __builtin_amdgcn_perm(__float_as_uint(p3), __float_as_uint(p2), 0x07060302);
        // logical chunk 2jk+(qd>>1), swizzled by row&7 = lm&7
        int sw = (2 * jk + (qd >> 1)) ^ pk_key;
        *(uint2*)&Ps[(w * 64 + g * 16 + lm) * 64 + sw * 8 + (qd & 1) * 4] = pk;
      }
    }

    // same-wave LDS RAW (wave w only touches its own 64 Ps rows)
    asm volatile("s_waitcnt lgkmcnt(0)" ::: "memory");

    // O += P V
#pragma unroll
    for (int h2 = 0; h2 < 2; ++h2) {
      bf16x8 pf[4];
#pragma unroll
      for (int g = 0; g < 4; ++g) {
        int sw = (h2 * 4 + qd) ^ pk_key;
        pf[g] = *(const bf16x8*)&Ps[(w * 64 + g * 16 + lm) * 64 + sw * 8];
      }
#pragma unroll
      for (int jn = 0; jn < 4; ++jn) {
        bf16x8 vf = *(const bf16x8*)&Vs2[h2 * 2048 + (jn * 16 + lm) * 32 + cs];
#pragma unroll
        for (int g = 0; g < 4; ++g)
          o[g][jn] = __builtin_amdgcn_mfma_f32_16x16x32_bf16(pf[g], vf, o[g][jn], 0, 0, 0);
      }
    }
  }

  // final row-sum reduce (over the 4 qd lane-groups) and normalize
#pragma unroll
  for (int g = 0; g < 4; ++g) {
    float l = psg[g];
    l += __shfl_xor(l, 16); l += __shfl_xor(l, 32);
    if (qd == 0) Ls[w * 64 + g * 16 + lm] = l;
  }
  asm volatile("s_waitcnt lgkmcnt(0)" ::: "memory");

  const int b = bh >> 4, hh = bh & 15;
#pragma unroll
  for (int g = 0; g < 4; ++g)
#pragma unroll
    for (int r = 0; r < 4; ++r) {
      float inv = 1.0f / Ls[w * 64 + g * 16 + qd * 4 + r];
      int qrow = q0 + w * 64 + g * 16 + qd * 4 + r;
#pragma unroll
      for (int jn = 0; jn < 4; ++jn)
        out[(size_t)(b * SEQ + qrow) * DIM + hh * HD + jn * 16 + lm] = o[g][jn][r] * inv;
    }
}

extern "C" void kernel_launch(void* const* d_in, const int* in_sizes, int n_in,
                              void* d_out, int out_size, void* d_ws, size_t ws_size,
                              hipStream_t stream) {
  const float* x  = (const float*)d_in[0];
  const float* Wq = (const float*)d_in[1];
  const float* bq = (const float*)d_in[2];
  const float* Wk = (const float*)d_in[3];
  const float* bk = (const float*)d_in[4];
  const float* Wv = (const float*)d_in[5];
  const float* bv = (const float*)d_in[6];
  float* out = (float*)d_out;

  unsigned short* ws = (unsigned short*)d_ws;
  const size_t XE = (size_t)BATCH * SEQ * DIM;   // 8388608
  const size_t WE = (size_t)DIM * DIM;           // 1048576
  unsigned short* xb  = ws;
  unsigned short* wqb = xb + XE;
  unsigned short* wkb = wqb + WE;
  unsigned short* wvb = wkb + WE;
  unsigned short* qb  = wvb + WE;
  unsigned short* kb  = qb + XE;
  unsigned short* vb  = kb + XE;

  const int total_groups = (int)(XE / 8 + 3 * (WE / 8));   // 1441792
  cast_all_kernel<<<total_groups / 256, 256, 0, stream>>>(
      x, Wq, Wk, Wv, xb, wqb, wkb, wvb);

  dim3 gg(32, 8, 3);
  gemm_qkv<<<gg, 512, 0, stream>>>(xb, wqb, wkb, wvb, bq, bk, bv, qb, kb, vb);

  dim3 fg(SEQ / 128, BATCH * NH);
  flash_kernel<<<fg, 128, 0, stream>>>(qb, kb, vb, out);
}